// Round 1
// baseline (1754.686 us; speedup 1.0000x reference)
//
#include <hip/hip_runtime.h>

#define NPTS 400000
#define NXv 352
#define NYv 400
#define CANVAS 281600  // 2 * 1 * 400 * 352

// ---------------- K1: scatter-sum of features + counts per voxel ----------------
__global__ void k_scatter(const float4* __restrict__ feat, const int4* __restrict__ coors,
                          int* __restrict__ idxbuf, float* __restrict__ vsum,
                          float* __restrict__ vcnt) {
    int i = blockIdx.x * 256 + threadIdx.x;
    if (i >= NPTS) return;
    int4 c = coors[i];                       // [b, z, y, x], NZ == 1
    int idx = ((c.x + c.y) * NYv + c.z) * NXv + c.w;
    idxbuf[i] = idx;
    float4 f = feat[i];
    atomicAdd(&vsum[idx * 4 + 0], f.x);
    atomicAdd(&vsum[idx * 4 + 1], f.y);
    atomicAdd(&vsum[idx * 4 + 2], f.z);
    atomicAdd(&vsum[idx * 4 + 3], f.w);
    atomicAdd(&vcnt[idx], 1.0f);
}

// ---------------- K2: build feat(10) and GEMM1 (10->64), store pre-BN x0 --------
__global__ void k_gemm1(const float4* __restrict__ feat, const int4* __restrict__ coors,
                        const int* __restrict__ idxbuf, const float4* __restrict__ vsum,
                        const float* __restrict__ vcnt, const float* __restrict__ W0,
                        float* __restrict__ x0) {
    __shared__ float w0s[640];
    for (int t = threadIdx.x; t < 640; t += 256) w0s[t] = W0[t];
    __syncthreads();
    int i = blockIdx.x * 256 + threadIdx.x;
    if (i >= NPTS) return;
    float4 f = feat[i];
    int idx = idxbuf[i];
    float cnt = fmaxf(vcnt[idx], 1.0f);
    float4 vs = vsum[idx];
    int4 c = coors[i];
    float ft[10];
    ft[0] = f.x; ft[1] = f.y; ft[2] = f.z; ft[3] = f.w;
    ft[4] = f.x - vs.x / cnt;
    ft[5] = f.y - vs.y / cnt;
    ft[6] = f.z - vs.z / cnt;
    ft[7] = f.x - ((float)c.w * 0.2f + 0.1f);            // VX/2 + PCR0 = 0.1
    ft[8] = f.y - ((float)c.z * 0.2f + (0.1f - 40.0f));  // VY/2 + PCR1
    ft[9] = f.z - ((float)c.y * 4.0f + (2.0f - 3.0f));   // VZ/2 + PCR2
    float* o = x0 + (size_t)i * 64;
    #pragma unroll
    for (int j = 0; j < 64; j += 4) {
        float4 a = make_float4(0.f, 0.f, 0.f, 0.f);
        #pragma unroll
        for (int k = 0; k < 10; ++k) {
            float fk = ft[k];
            a.x = fmaf(fk, w0s[k * 64 + j + 0], a.x);
            a.y = fmaf(fk, w0s[k * 64 + j + 1], a.y);
            a.z = fmaf(fk, w0s[k * 64 + j + 2], a.z);
            a.w = fmaf(fk, w0s[k * 64 + j + 3], a.w);
        }
        *(float4*)(o + j) = a;
    }
}

// ---------------- column sum / sum-of-squares over N rows -----------------------
template <int C>
__global__ void k_colstats(const float* __restrict__ x, float* __restrict__ sums) {
    const int ROWS = 256 / C;
    int col = threadIdx.x & (C - 1);
    int sub = threadIdx.x / C;
    float s = 0.f, q = 0.f;
    for (int r = blockIdx.x * ROWS + sub; r < NPTS; r += gridDim.x * ROWS) {
        float v = x[(size_t)r * C + col];
        s += v;
        q = fmaf(v, v, q);
    }
    __shared__ float sh[512];
    sh[threadIdx.x] = s;
    sh[256 + threadIdx.x] = q;
    __syncthreads();
    if (sub == 0) {
        #pragma unroll
        for (int k = 1; k < ROWS; ++k) {
            s += sh[col + k * C];
            q += sh[256 + col + k * C];
        }
        atomicAdd(&sums[col], s);
        atomicAdd(&sums[C + col], q);
    }
}

// ---------------- BN finalize: scale = g/sqrt(var+eps), shift = b - mu*scale ----
__global__ void k_bnfin(const float* __restrict__ sums, const float* __restrict__ g,
                        const float* __restrict__ b, float* __restrict__ ss, int C,
                        float invN) {
    int j = threadIdx.x;
    if (j >= C) return;
    float mu = sums[j] * invN;
    float var = sums[C + j] * invN - mu * mu;
    float istd = 1.0f / sqrtf(var + 1e-3f);
    float scale = istd * g[j];
    ss[j] = scale;
    ss[C + j] = b[j] - mu * scale;
}

// ---------------- apply BN+ReLU in place + atomicMax into v0 (64 cols) ----------
__global__ void k_apply0(float* __restrict__ x0, const int* __restrict__ idxbuf,
                         const float* __restrict__ ss, unsigned int* __restrict__ v0) {
    __shared__ float s[128];
    if (threadIdx.x < 128) s[threadIdx.x] = ss[threadIdx.x];
    __syncthreads();
    int i = blockIdx.x * 256 + threadIdx.x;
    if (i >= NPTS * 16) return;
    int p = i >> 4;
    int c = (i & 15) << 2;
    float4 v = *(float4*)(x0 + (size_t)p * 64 + c);
    v.x = fmaxf(fmaf(v.x, s[c + 0], s[64 + c + 0]), 0.f);
    v.y = fmaxf(fmaf(v.y, s[c + 1], s[64 + c + 1]), 0.f);
    v.z = fmaxf(fmaf(v.z, s[c + 2], s[64 + c + 2]), 0.f);
    v.w = fmaxf(fmaf(v.w, s[c + 3], s[64 + c + 3]), 0.f);
    *(float4*)(x0 + (size_t)p * 64 + c) = v;
    unsigned int* dst = v0 + (size_t)idxbuf[p] * 64 + c;
    // post-ReLU values are >= 0, so uint bit-pattern max == float max; v0 zeroed
    atomicMax(dst + 0, __float_as_uint(v.x));
    atomicMax(dst + 1, __float_as_uint(v.y));
    atomicMax(dst + 2, __float_as_uint(v.z));
    atomicMax(dst + 3, __float_as_uint(v.w));
}

// ---------------- GEMM2: (N,128) @ (128,128), f1 = [pf0 | v0[idx]] --------------
__global__ void k_gemm2(const float* __restrict__ pf0, const float* __restrict__ v0,
                        const int* __restrict__ idxbuf, const float* __restrict__ W1,
                        float* __restrict__ x1) {
    int p = blockIdx.x * 256 + threadIdx.x;
    if (p >= NPTS) return;
    const float4* f0 = (const float4*)(pf0 + (size_t)p * 64);
    const float4* g0 = (const float4*)(v0 + (size_t)idxbuf[p] * 64);
    float* out = x1 + (size_t)p * 128;
    for (int h = 0; h < 2; ++h) {
        float acc[64];
        #pragma unroll
        for (int j = 0; j < 64; ++j) acc[j] = 0.f;
        #pragma unroll 1
        for (int kc = 0; kc < 32; ++kc) {
            float4 fk = (kc < 16) ? f0[kc] : g0[kc - 16];
            const float* wr = W1 + kc * 4 * 128 + h * 64;  // wave-uniform -> s_load
            #pragma unroll
            for (int j = 0; j < 64; ++j) {
                acc[j] = fmaf(fk.x, wr[0 * 128 + j], acc[j]);
                acc[j] = fmaf(fk.y, wr[1 * 128 + j], acc[j]);
                acc[j] = fmaf(fk.z, wr[2 * 128 + j], acc[j]);
                acc[j] = fmaf(fk.w, wr[3 * 128 + j], acc[j]);
            }
        }
        #pragma unroll
        for (int j = 0; j < 64; j += 4)
            *(float4*)(out + h * 64 + j) =
                make_float4(acc[j], acc[j + 1], acc[j + 2], acc[j + 3]);
    }
}

// ---------------- apply BN+ReLU + atomicMax into dense output (128 cols) --------
__global__ void k_apply1(const float* __restrict__ x1, const int* __restrict__ idxbuf,
                         const float* __restrict__ ss, unsigned int* __restrict__ out) {
    __shared__ float s[256];
    s[threadIdx.x] = ss[threadIdx.x];
    __syncthreads();
    int i = blockIdx.x * 256 + threadIdx.x;
    if (i >= NPTS * 32) return;
    int p = i >> 5;
    int c = (i & 31) << 2;
    float4 v = *(const float4*)(x1 + (size_t)p * 128 + c);
    float4 r;
    r.x = fmaxf(fmaf(v.x, s[c + 0], s[128 + c + 0]), 0.f);
    r.y = fmaxf(fmaf(v.y, s[c + 1], s[128 + c + 1]), 0.f);
    r.z = fmaxf(fmaf(v.z, s[c + 2], s[128 + c + 2]), 0.f);
    r.w = fmaxf(fmaf(v.w, s[c + 3], s[128 + c + 3]), 0.f);
    unsigned int* dst = out + (size_t)idxbuf[p] * 128 + c;
    atomicMax(dst + 0, __float_as_uint(r.x));
    atomicMax(dst + 1, __float_as_uint(r.y));
    atomicMax(dst + 2, __float_as_uint(r.z));
    atomicMax(dst + 3, __float_as_uint(r.w));
}

extern "C" void kernel_launch(void* const* d_in, const int* in_sizes, int n_in,
                              void* d_out, int out_size, void* d_ws, size_t ws_size,
                              hipStream_t stream) {
    const float4* feat  = (const float4*)d_in[0];
    const int4*   coors = (const int4*)d_in[1];
    const float*  W0    = (const float*)d_in[2];
    const float*  g0    = (const float*)d_in[3];
    const float*  b0    = (const float*)d_in[4];
    const float*  W1    = (const float*)d_in[5];
    const float*  g1    = (const float*)d_in[6];
    const float*  b1    = (const float*)d_in[7];

    char* ws = (char*)d_ws;
    // workspace layout (bytes)
    int*   idxbuf = (int*)(ws + 0);                          // 1,600,000
    float* vsum   = (float*)(ws + 1600000);                  // 4,505,600
    float* vcnt   = (float*)(ws + 6105600);                  // 1,126,400
    float* stats  = (float*)(ws + 7232000);                  // 768 floats:
    //   [0:64] sum0, [64:128] sq0, [128:256] sum1, [256:384] sq1,
    //   [384:512] ss0 (scale|shift), [512:768] ss1 (scale|shift)
    float* x0     = (float*)(ws + 7235072);                  // 102,400,000 (pre-BN -> pf0 in place)
    float* v0     = (float*)(ws + 109635072);                // 72,089,600
    float* x1     = (float*)(ws + 181724672);                // 204,800,000
    // total: 386,524,672 bytes

    // zero the accumulator regions (ws/d_out are poisoned before every call)
    hipMemsetAsync(ws + 1600000, 0, 5632000, stream);              // vsum + vcnt
    hipMemsetAsync(stats, 0, 384 * sizeof(float), stream);         // sums/sumsqs
    hipMemsetAsync(v0, 0, 72089600, stream);                       // v0
    hipMemsetAsync(d_out, 0, (size_t)out_size * sizeof(float), stream);

    const int BLK = 256;
    int gpts = (NPTS + BLK - 1) / BLK;  // 1563

    k_scatter<<<gpts, BLK, 0, stream>>>(feat, coors, idxbuf, vsum, vcnt);
    k_gemm1<<<gpts, BLK, 0, stream>>>(feat, coors, idxbuf, (const float4*)vsum, vcnt, W0, x0);
    k_colstats<64><<<1024, BLK, 0, stream>>>(x0, stats);
    k_bnfin<<<1, 128, 0, stream>>>(stats, g0, b0, stats + 384, 64, 1.0f / NPTS);
    k_apply0<<<(NPTS * 16) / BLK, BLK, 0, stream>>>(x0, idxbuf, stats + 384, (unsigned int*)v0);
    k_gemm2<<<gpts, BLK, 0, stream>>>(x0, v0, idxbuf, W1, x1);
    k_colstats<128><<<1024, BLK, 0, stream>>>(x1, stats + 128);
    k_bnfin<<<1, 128, 0, stream>>>(stats + 128, g1, b1, stats + 512, 128, 1.0f / NPTS);
    k_apply1<<<(NPTS * 32) / BLK, BLK, 0, stream>>>(x1, idxbuf, stats + 512, (unsigned int*)d_out);
}

// Round 2
// 985.028 us; speedup vs baseline: 1.7814x; 1.7814x over previous
//
#include <hip/hip_runtime.h>

#define NPTS 400000
#define NXv 352
#define NYv 400
#define CANVAS 281600  // 2 * 1 * 400 * 352
#define CAP 16         // max tracked points per voxel (Poisson lambda=1.42; P(>=16)~1e-6 device-wide)

typedef unsigned int uint;
typedef unsigned short ushort;

// round-to-nearest-even float -> bf16 pack of two values into one uint (a=low, b=high)
__device__ inline uint packbf(float a, float b) {
    uint ua = __float_as_uint(a);
    ua = (ua + 0x7fffu + ((ua >> 16) & 1u)) >> 16;
    uint ub = __float_as_uint(b);
    ub = (ub + 0x7fffu + ((ub >> 16) & 1u)) & 0xffff0000u;
    return ua | ub;
}

// ---------------- K1: bucket build + scatter-sum of features --------------------
__global__ void k_bucket(const float4* __restrict__ feat, const int4* __restrict__ coors,
                         int* __restrict__ idxbuf, float* __restrict__ vsum,
                         int* __restrict__ ucnt, int* __restrict__ slot) {
    int i = blockIdx.x * 256 + threadIdx.x;
    if (i >= NPTS) return;
    int4 c = coors[i];                       // [b, z, y, x], NZ == 1
    int idx = ((c.x + c.y) * NYv + c.z) * NXv + c.w;
    idxbuf[i] = idx;
    float4 f = feat[i];
    atomicAdd(&vsum[idx * 4 + 0], f.x);
    atomicAdd(&vsum[idx * 4 + 1], f.y);
    atomicAdd(&vsum[idx * 4 + 2], f.z);
    atomicAdd(&vsum[idx * 4 + 3], f.w);
    int pos = atomicAdd(&ucnt[idx], 1);
    if (pos < CAP) slot[idx * CAP + pos] = i;
}

// ---------------- K2: build feat(10) and GEMM1 (10->64), store pre-BN x0 --------
__global__ void k_gemm1(const float4* __restrict__ feat, const int4* __restrict__ coors,
                        const int* __restrict__ idxbuf, const float4* __restrict__ vsum,
                        const int* __restrict__ ucnt, const float* __restrict__ W0,
                        float* __restrict__ x0) {
    __shared__ float w0s[640];
    for (int t = threadIdx.x; t < 640; t += 256) w0s[t] = W0[t];
    __syncthreads();
    int i = blockIdx.x * 256 + threadIdx.x;
    if (i >= NPTS) return;
    float4 f = feat[i];
    int idx = idxbuf[i];
    float cnt = (float)max(ucnt[idx], 1);
    float4 vs = vsum[idx];
    int4 c = coors[i];
    float ft[10];
    ft[0] = f.x; ft[1] = f.y; ft[2] = f.z; ft[3] = f.w;
    ft[4] = f.x - vs.x / cnt;
    ft[5] = f.y - vs.y / cnt;
    ft[6] = f.z - vs.z / cnt;
    ft[7] = f.x - ((float)c.w * 0.2f + 0.1f);            // VX/2 + PCR0
    ft[8] = f.y - ((float)c.z * 0.2f + (0.1f - 40.0f));  // VY/2 + PCR1
    ft[9] = f.z - ((float)c.y * 4.0f + (2.0f - 3.0f));   // VZ/2 + PCR2
    float* o = x0 + (size_t)i * 64;
    #pragma unroll
    for (int j = 0; j < 64; j += 4) {
        float4 a = make_float4(0.f, 0.f, 0.f, 0.f);
        #pragma unroll
        for (int k = 0; k < 10; ++k) {
            float fk = ft[k];
            a.x = fmaf(fk, w0s[k * 64 + j + 0], a.x);
            a.y = fmaf(fk, w0s[k * 64 + j + 1], a.y);
            a.z = fmaf(fk, w0s[k * 64 + j + 2], a.z);
            a.w = fmaf(fk, w0s[k * 64 + j + 3], a.w);
        }
        *(float4*)(o + j) = a;
    }
}

// ---------------- column sum / sum-of-squares over N rows (fp32 input) ----------
template <int C>
__global__ void k_colstats(const float* __restrict__ x, float* __restrict__ sums) {
    const int ROWS = 256 / C;
    int col = threadIdx.x & (C - 1);
    int sub = threadIdx.x / C;
    float s = 0.f, q = 0.f;
    for (int r = blockIdx.x * ROWS + sub; r < NPTS; r += gridDim.x * ROWS) {
        float v = x[(size_t)r * C + col];
        s += v;
        q = fmaf(v, v, q);
    }
    __shared__ float sh[512];
    sh[threadIdx.x] = s;
    sh[256 + threadIdx.x] = q;
    __syncthreads();
    if (sub == 0) {
        #pragma unroll
        for (int k = 1; k < ROWS; ++k) {
            s += sh[col + k * C];
            q += sh[256 + col + k * C];
        }
        atomicAdd(&sums[col], s);
        atomicAdd(&sums[C + col], q);
    }
}

// ---------------- column stats over bf16-packed x1 (128 cols = 64 uints) --------
__global__ void k_colstats1(const uint* __restrict__ x1u, float* __restrict__ sums) {
    int cp = threadIdx.x & 63;   // column pair -> cols 2cp, 2cp+1
    int sub = threadIdx.x >> 6;  // 0..3
    float s0 = 0.f, s1 = 0.f, q0 = 0.f, q1 = 0.f;
    for (int r = blockIdx.x * 4 + sub; r < NPTS; r += gridDim.x * 4) {
        uint u = x1u[(size_t)r * 64 + cp];
        float a = __uint_as_float(u << 16);
        float b = __uint_as_float(u & 0xffff0000u);
        s0 += a; q0 = fmaf(a, a, q0);
        s1 += b; q1 = fmaf(b, b, q1);
    }
    __shared__ float sh[1024];
    sh[threadIdx.x] = s0; sh[256 + threadIdx.x] = q0;
    sh[512 + threadIdx.x] = s1; sh[768 + threadIdx.x] = q1;
    __syncthreads();
    if (sub == 0) {
        #pragma unroll
        for (int k = 1; k < 4; ++k) {
            s0 += sh[cp + k * 64];       q0 += sh[256 + cp + k * 64];
            s1 += sh[512 + cp + k * 64]; q1 += sh[768 + cp + k * 64];
        }
        atomicAdd(&sums[2 * cp + 0], s0);
        atomicAdd(&sums[2 * cp + 1], s1);
        atomicAdd(&sums[128 + 2 * cp + 0], q0);
        atomicAdd(&sums[128 + 2 * cp + 1], q1);
    }
}

// ---------------- BN finalize: scale = g/sqrt(var+eps), shift = b - mu*scale ----
__global__ void k_bnfin(const float* __restrict__ sums, const float* __restrict__ g,
                        const float* __restrict__ b, float* __restrict__ ss, int C,
                        float invN) {
    int j = threadIdx.x;
    if (j >= C) return;
    float mu = sums[j] * invN;
    float var = sums[C + j] * invN - mu * mu;
    float istd = 1.0f / sqrtf(var + 1e-3f);
    float scale = istd * g[j];
    ss[j] = scale;
    ss[C + j] = b[j] - mu * scale;
}

// ---------------- gather-max over voxel point lists, BN+ReLU on the fly ---------
// 16 threads per voxel, 4 cols each; relu(max(x)) == max(relu(x)), empty -> 0
__global__ void k_vmax0(const float* __restrict__ x0, const int* __restrict__ ucnt,
                        const int* __restrict__ slot, const float* __restrict__ ss,
                        float* __restrict__ v0) {
    __shared__ float s[128];
    if (threadIdx.x < 128) s[threadIdx.x] = ss[threadIdx.x];
    __syncthreads();
    int t = blockIdx.x * 256 + threadIdx.x;
    int v = t >> 4;
    if (v >= CANVAS) return;
    int c = (t & 15) << 2;
    int n = min(ucnt[v], CAP);
    float4 m = make_float4(0.f, 0.f, 0.f, 0.f);
    for (int j = 0; j < n; ++j) {
        int p = slot[v * CAP + j];
        float4 x = *(const float4*)(x0 + (size_t)p * 64 + c);
        m.x = fmaxf(m.x, fmaf(x.x, s[c + 0], s[64 + c + 0]));
        m.y = fmaxf(m.y, fmaf(x.y, s[c + 1], s[64 + c + 1]));
        m.z = fmaxf(m.z, fmaf(x.z, s[c + 2], s[64 + c + 2]));
        m.w = fmaxf(m.w, fmaf(x.w, s[c + 3], s[64 + c + 3]));
    }
    *(float4*)(v0 + (size_t)v * 64 + c) = m;
}

// ---------------- GEMM2: (N,128)@(128,128); f1 = [bnrelu(x0) | v0[idx]] ---------
__global__ void k_gemm2(const float* __restrict__ x0, const float* __restrict__ v0,
                        const int* __restrict__ idxbuf, const float* __restrict__ ss,
                        const float* __restrict__ W1, uint* __restrict__ x1u) {
    __shared__ float s[128];
    if (threadIdx.x < 128) s[threadIdx.x] = ss[threadIdx.x];
    __syncthreads();
    int p = blockIdx.x * 256 + threadIdx.x;
    if (p >= NPTS) return;
    const float4* f0 = (const float4*)(x0 + (size_t)p * 64);
    const float4* g0 = (const float4*)(v0 + (size_t)idxbuf[p] * 64);
    for (int h = 0; h < 2; ++h) {
        float acc[64];
        #pragma unroll
        for (int j = 0; j < 64; ++j) acc[j] = 0.f;
        #pragma unroll 1
        for (int kc = 0; kc < 32; ++kc) {
            float4 fk;
            if (kc < 16) {
                float4 x = f0[kc];
                int c = kc * 4;
                fk.x = fmaxf(fmaf(x.x, s[c + 0], s[64 + c + 0]), 0.f);
                fk.y = fmaxf(fmaf(x.y, s[c + 1], s[64 + c + 1]), 0.f);
                fk.z = fmaxf(fmaf(x.z, s[c + 2], s[64 + c + 2]), 0.f);
                fk.w = fmaxf(fmaf(x.w, s[c + 3], s[64 + c + 3]), 0.f);
            } else {
                fk = g0[kc - 16];
            }
            const float* wr = W1 + kc * 4 * 128 + h * 64;  // wave-uniform -> s_load
            #pragma unroll
            for (int j = 0; j < 64; ++j) {
                acc[j] = fmaf(fk.x, wr[0 * 128 + j], acc[j]);
                acc[j] = fmaf(fk.y, wr[1 * 128 + j], acc[j]);
                acc[j] = fmaf(fk.z, wr[2 * 128 + j], acc[j]);
                acc[j] = fmaf(fk.w, wr[3 * 128 + j], acc[j]);
            }
        }
        uint4* orow = (uint4*)(x1u + (size_t)p * 64 + h * 32);
        #pragma unroll
        for (int j = 0; j < 64; j += 8) {
            uint4 w;
            w.x = packbf(acc[j + 0], acc[j + 1]);
            w.y = packbf(acc[j + 2], acc[j + 3]);
            w.z = packbf(acc[j + 4], acc[j + 5]);
            w.w = packbf(acc[j + 6], acc[j + 7]);
            orow[j >> 3] = w;
        }
    }
}

// ---------------- final gather-max -> dense output, BN+ReLU on the fly ----------
// 32 threads per voxel, 4 cols each (one uint2 = 4 bf16 per point read)
__global__ void k_vmax1(const uint2* __restrict__ x1u, const int* __restrict__ ucnt,
                        const int* __restrict__ slot, const float* __restrict__ ss,
                        float4* __restrict__ out) {
    __shared__ float s[256];
    s[threadIdx.x] = ss[threadIdx.x];
    __syncthreads();
    int t = blockIdx.x * 256 + threadIdx.x;
    int v = t >> 5;
    if (v >= CANVAS) return;
    int c = (t & 31) << 2;
    int n = min(ucnt[v], CAP);
    float4 m = make_float4(0.f, 0.f, 0.f, 0.f);
    for (int j = 0; j < n; ++j) {
        int p = slot[v * CAP + j];
        uint2 u = x1u[(size_t)p * 32 + (c >> 2)];
        float a0 = __uint_as_float(u.x << 16);
        float a1 = __uint_as_float(u.x & 0xffff0000u);
        float a2 = __uint_as_float(u.y << 16);
        float a3 = __uint_as_float(u.y & 0xffff0000u);
        m.x = fmaxf(m.x, fmaf(a0, s[c + 0], s[128 + c + 0]));
        m.y = fmaxf(m.y, fmaf(a1, s[c + 1], s[128 + c + 1]));
        m.z = fmaxf(m.z, fmaf(a2, s[c + 2], s[128 + c + 2]));
        m.w = fmaxf(m.w, fmaf(a3, s[c + 3], s[128 + c + 3]));
    }
    out[(size_t)v * 32 + (c >> 2)] = m;
}

extern "C" void kernel_launch(void* const* d_in, const int* in_sizes, int n_in,
                              void* d_out, int out_size, void* d_ws, size_t ws_size,
                              hipStream_t stream) {
    const float4* feat  = (const float4*)d_in[0];
    const int4*   coors = (const int4*)d_in[1];
    const float*  W0    = (const float*)d_in[2];
    const float*  g0    = (const float*)d_in[3];
    const float*  b0    = (const float*)d_in[4];
    const float*  W1    = (const float*)d_in[5];
    const float*  g1    = (const float*)d_in[6];
    const float*  b1    = (const float*)d_in[7];

    char* ws = (char*)d_ws;
    // workspace layout (bytes)
    int*   idxbuf = (int*)(ws + 0);                 //   1,600,000
    float* vsum   = (float*)(ws + 1600000);         //   4,505,600
    int*   ucnt   = (int*)(ws + 6105600);           //   1,126,400
    float* stats  = (float*)(ws + 7232000);         //   768 floats:
    //   [0:64] sum0, [64:128] sq0, [128:256] sum1, [256:384] sq1,
    //   [384:512] ss0 (scale|shift), [512:768] ss1 (scale|shift)
    int*   slot   = (int*)(ws + 7235072);           //  18,022,400 (CANVAS*CAP*4)
    float* x0     = (float*)(ws + 25257472);        // 102,400,000 (pre-BN)
    float* v0     = (float*)(ws + 127657472);       //  72,089,600 (post-BN-ReLU max)
    uint*  x1u    = (uint*)(ws + 199747072);        // 102,400,000 (pre-BN, bf16 packed)
    // total: 302,147,072 bytes

    // zero only the accumulator regions (vsum+ucnt contiguous, and sums)
    hipMemsetAsync(ws + 1600000, 0, 5632000, stream);
    hipMemsetAsync(stats, 0, 384 * sizeof(float), stream);

    const int BLK = 256;
    int gpts = (NPTS + BLK - 1) / BLK;  // 1563

    k_bucket<<<gpts, BLK, 0, stream>>>(feat, coors, idxbuf, vsum, ucnt, slot);
    k_gemm1<<<gpts, BLK, 0, stream>>>(feat, coors, idxbuf, (const float4*)vsum, ucnt, W0, x0);
    k_colstats<64><<<1024, BLK, 0, stream>>>(x0, stats);
    k_bnfin<<<1, 64, 0, stream>>>(stats, g0, b0, stats + 384, 64, 1.0f / NPTS);
    k_vmax0<<<CANVAS * 16 / BLK, BLK, 0, stream>>>(x0, ucnt, slot, stats + 384, v0);
    k_gemm2<<<gpts, BLK, 0, stream>>>(x0, v0, idxbuf, stats + 384, W1, x1u);
    k_colstats1<<<1024, BLK, 0, stream>>>(x1u, stats + 128);
    k_bnfin<<<1, 128, 0, stream>>>(stats + 128, g1, b1, stats + 512, 128, 1.0f / NPTS);
    k_vmax1<<<CANVAS * 32 / BLK, BLK, 0, stream>>>((const uint2*)x1u, ucnt, slot,
                                                   stats + 512, (float4*)d_out);
}

// Round 3
// 592.768 us; speedup vs baseline: 2.9602x; 1.6617x over previous
//
#include <hip/hip_runtime.h>

#define NPTS 400000
#define NXv 352
#define NYv 400
#define CANVAS 281600  // 2 * 1 * 400 * 352
#define CAP 16         // max tracked points per voxel (Poisson lambda=1.42)

typedef unsigned int uint;
typedef unsigned short ushort;
typedef __attribute__((ext_vector_type(8))) short short8;   // 8 bf16 (4 VGPRs)
typedef __attribute__((ext_vector_type(4))) float floatx4;  // MFMA acc

// round-to-nearest-even float -> bf16 pack of two values into one uint (a=low, b=high)
__device__ inline uint packbf(float a, float b) {
    uint ua = __float_as_uint(a);
    ua = (ua + 0x7fffu + ((ua >> 16) & 1u)) >> 16;
    uint ub = __float_as_uint(b);
    ub = (ub + 0x7fffu + ((ub >> 16) & 1u)) & 0xffff0000u;
    return ua | ub;
}
__device__ inline ushort bf16bits(float a) {
    uint u = __float_as_uint(a);
    return (ushort)((u + 0x7fffu + ((u >> 16) & 1u)) >> 16);
}
__device__ inline float lo16(uint u) { return __uint_as_float(u << 16); }
__device__ inline float hi16(uint u) { return __uint_as_float(u & 0xffff0000u); }

// ---------------- K1: bucket build + scatter-sum of features --------------------
__global__ void k_bucket(const float4* __restrict__ feat, const int4* __restrict__ coors,
                         int* __restrict__ idxbuf, float* __restrict__ vsum,
                         int* __restrict__ ucnt, int* __restrict__ slot) {
    int i = blockIdx.x * 256 + threadIdx.x;
    if (i >= NPTS) return;
    int4 c = coors[i];                       // [b, z, y, x], NZ == 1
    int idx = ((c.x + c.y) * NYv + c.z) * NXv + c.w;
    idxbuf[i] = idx;
    float4 f = feat[i];
    atomicAdd(&vsum[idx * 4 + 0], f.x);
    atomicAdd(&vsum[idx * 4 + 1], f.y);
    atomicAdd(&vsum[idx * 4 + 2], f.z);
    atomicAdd(&vsum[idx * 4 + 3], f.w);
    int pos = atomicAdd(&ucnt[idx], 1);
    if (pos < CAP) slot[idx * CAP + pos] = i;
}

// ---------------- W1 (128x128 f32, KxN) -> W1T bf16 (NxK) -----------------------
__global__ void k_prepw(const float* __restrict__ W1, ushort* __restrict__ w1t) {
    int i = blockIdx.x * 256 + threadIdx.x;
    if (i >= 16384) return;
    int n = i & 127, k = i >> 7;
    w1t[n * 128 + k] = bf16bits(W1[k * 128 + n]);
}

// ---------------- K2: build feat(10), GEMM1 (10->64), store pre-BN x0 bf16 ------
__global__ void k_gemm1(const float4* __restrict__ feat, const int4* __restrict__ coors,
                        const int* __restrict__ idxbuf, const float4* __restrict__ vsum,
                        const int* __restrict__ ucnt, const float* __restrict__ W0,
                        uint* __restrict__ x0u) {
    __shared__ float w0s[640];
    for (int t = threadIdx.x; t < 640; t += 256) w0s[t] = W0[t];
    __syncthreads();
    int i = blockIdx.x * 256 + threadIdx.x;
    if (i >= NPTS) return;
    float4 f = feat[i];
    int idx = idxbuf[i];
    float cnt = (float)max(ucnt[idx], 1);
    float4 vs = vsum[idx];
    int4 c = coors[i];
    float ft[10];
    ft[0] = f.x; ft[1] = f.y; ft[2] = f.z; ft[3] = f.w;
    ft[4] = f.x - vs.x / cnt;
    ft[5] = f.y - vs.y / cnt;
    ft[6] = f.z - vs.z / cnt;
    ft[7] = f.x - ((float)c.w * 0.2f + 0.1f);            // VX/2 + PCR0
    ft[8] = f.y - ((float)c.z * 0.2f + (0.1f - 40.0f));  // VY/2 + PCR1
    ft[9] = f.z - ((float)c.y * 4.0f + (2.0f - 3.0f));   // VZ/2 + PCR2
    uint* o = x0u + (size_t)i * 32;
    #pragma unroll
    for (int g = 0; g < 8; ++g) {
        float a[8];
        #pragma unroll
        for (int j = 0; j < 8; ++j) a[j] = 0.f;
        #pragma unroll
        for (int k = 0; k < 10; ++k) {
            float fk = ft[k];
            #pragma unroll
            for (int j = 0; j < 8; ++j) a[j] = fmaf(fk, w0s[k * 64 + g * 8 + j], a[j]);
        }
        uint4 w;
        w.x = packbf(a[0], a[1]); w.y = packbf(a[2], a[3]);
        w.z = packbf(a[4], a[5]); w.w = packbf(a[6], a[7]);
        *(uint4*)(o + g * 4) = w;
    }
}

// ---------------- column stats over bf16-packed matrix (2 cols per uint) --------
template <int CU_>  // uints per row: 32 (64 cols) or 64 (128 cols)
__global__ void k_colstats_bf(const uint* __restrict__ x, float* __restrict__ sums) {
    const int SUBS = 256 / CU_;
    int cp = threadIdx.x & (CU_ - 1);
    int sub = threadIdx.x / CU_;
    float s0 = 0.f, s1 = 0.f, q0 = 0.f, q1 = 0.f;
    for (int r = blockIdx.x * SUBS + sub; r < NPTS; r += gridDim.x * SUBS) {
        uint u = x[(size_t)r * CU_ + cp];
        float a = lo16(u), b = hi16(u);
        s0 += a; q0 = fmaf(a, a, q0);
        s1 += b; q1 = fmaf(b, b, q1);
    }
    __shared__ float sh[1024];
    sh[threadIdx.x] = s0; sh[256 + threadIdx.x] = q0;
    sh[512 + threadIdx.x] = s1; sh[768 + threadIdx.x] = q1;
    __syncthreads();
    if (sub == 0) {
        #pragma unroll
        for (int k = 1; k < SUBS; ++k) {
            s0 += sh[cp + k * CU_];       q0 += sh[256 + cp + k * CU_];
            s1 += sh[512 + cp + k * CU_]; q1 += sh[768 + cp + k * CU_];
        }
        atomicAdd(&sums[2 * cp + 0], s0);
        atomicAdd(&sums[2 * cp + 1], s1);
        atomicAdd(&sums[2 * CU_ + 2 * cp + 0], q0);
        atomicAdd(&sums[2 * CU_ + 2 * cp + 1], q1);
    }
}

// ---------------- BN finalize: scale = g/sqrt(var+eps), shift = b - mu*scale ----
__global__ void k_bnfin(const float* __restrict__ sums, const float* __restrict__ g,
                        const float* __restrict__ b, float* __restrict__ ss, int C,
                        float invN) {
    int j = threadIdx.x;
    if (j >= C) return;
    float mu = sums[j] * invN;
    float var = sums[C + j] * invN - mu * mu;
    float istd = 1.0f / sqrtf(var + 1e-3f);
    float scale = istd * g[j];
    ss[j] = scale;
    ss[C + j] = b[j] - mu * scale;
}

// ---------------- gather-max over voxel lists, BN0+ReLU on the fly, bf16 out ----
__global__ void k_vmax0(const uint* __restrict__ x0u, const int* __restrict__ ucnt,
                        const int* __restrict__ slot, const float* __restrict__ ss,
                        uint* __restrict__ v0u) {
    __shared__ float s[128];
    if (threadIdx.x < 128) s[threadIdx.x] = ss[threadIdx.x];
    __syncthreads();
    int t = blockIdx.x * 256 + threadIdx.x;
    int v = t >> 4;
    if (v >= CANVAS) return;
    int c = (t & 15) << 2;
    int n = min(ucnt[v], CAP);
    float4 m = make_float4(0.f, 0.f, 0.f, 0.f);
    for (int j = 0; j < n; ++j) {
        int p = slot[v * CAP + j];
        uint2 u = *(const uint2*)(x0u + (size_t)p * 32 + (c >> 1));
        m.x = fmaxf(m.x, fmaf(lo16(u.x), s[c + 0], s[64 + c + 0]));
        m.y = fmaxf(m.y, fmaf(hi16(u.x), s[c + 1], s[64 + c + 1]));
        m.z = fmaxf(m.z, fmaf(lo16(u.y), s[c + 2], s[64 + c + 2]));
        m.w = fmaxf(m.w, fmaf(hi16(u.y), s[c + 3], s[64 + c + 3]));
    }
    uint2 o; o.x = packbf(m.x, m.y); o.y = packbf(m.z, m.w);
    *(uint2*)(v0u + (size_t)v * 32 + (c >> 1)) = o;
}

// ---------------- GEMM2 via MFMA: x1 = [bnrelu0(x0) | v0[idx]] @ W1, bf16 out ---
// block = 256 thr (4 waves), strip = 64 points; wave w -> rows [16w,16w+16) x 128 cols
__global__ __launch_bounds__(256) void k_gemm2m(
        const uint* __restrict__ x0u, const uint* __restrict__ v0u,
        const int* __restrict__ idxbuf, const float* __restrict__ ss,
        const ushort* __restrict__ w1t, uint* __restrict__ x1u) {
    __shared__ __align__(16) ushort Bs[128 * 136];  // W1T, row pad +8 -> bank offset 4/row
    __shared__ __align__(16) ushort As[64 * 136];   // A tile, reused as C tile
    __shared__ float s[128];
    __shared__ int idxs[64];

    int r0 = blockIdx.x * 64;
    for (int i = threadIdx.x; i < 2048; i += 256) {  // 128 rows x 16 chunks(8 u16)
        int r = i >> 4, ch = i & 15;
        *(uint4*)&Bs[r * 136 + ch * 8] = *(const uint4*)&w1t[r * 128 + ch * 8];
    }
    if (threadIdx.x < 128) s[threadIdx.x] = ss[threadIdx.x];
    if (threadIdx.x < 64) idxs[threadIdx.x] = idxbuf[r0 + threadIdx.x];
    __syncthreads();

    // A cols [0:64) = bnrelu0(x0) ; cols [64:128) = v0[idx] (already post-BN0)
    for (int i = threadIdx.x; i < 512; i += 256) {   // 64 rows x 8 chunks
        int r = i >> 3, ch = i & 7, cb = ch * 8;
        uint4 u = *(const uint4*)(x0u + (size_t)(r0 + r) * 32 + ch * 4);
        uint w[4] = {u.x, u.y, u.z, u.w}, o[4];
        #pragma unroll
        for (int q2 = 0; q2 < 4; ++q2) {
            float a = fmaxf(fmaf(lo16(w[q2]), s[cb + 2 * q2], s[64 + cb + 2 * q2]), 0.f);
            float b = fmaxf(fmaf(hi16(w[q2]), s[cb + 2 * q2 + 1], s[64 + cb + 2 * q2 + 1]), 0.f);
            o[q2] = packbf(a, b);
        }
        *(uint4*)&As[r * 136 + ch * 8] = make_uint4(o[0], o[1], o[2], o[3]);
    }
    for (int i = threadIdx.x; i < 512; i += 256) {
        int r = i >> 3, ch = i & 7;
        *(uint4*)&As[r * 136 + 64 + ch * 8] =
            *(const uint4*)(v0u + (size_t)idxs[r] * 32 + ch * 4);
    }
    __syncthreads();

    int lane = threadIdx.x & 63, wid = threadIdx.x >> 6;
    int m = lane & 15, q = lane >> 4;  // A[m][k=q*8+j]; B[n=m'][k]; C col=m', row=q*4+reg
    const ushort* ar = &As[(wid * 16 + m) * 136 + q * 8];
    short8 a0 = *(const short8*)&ar[0];
    short8 a1 = *(const short8*)&ar[32];
    short8 a2 = *(const short8*)&ar[64];
    short8 a3 = *(const short8*)&ar[96];
    __syncthreads();  // all waves done reading As; reuse it for C

    #pragma unroll
    for (int ct = 0; ct < 8; ++ct) {
        const ushort* br = &Bs[(ct * 16 + m) * 136 + q * 8];
        short8 b0 = *(const short8*)&br[0];
        short8 b1 = *(const short8*)&br[32];
        short8 b2 = *(const short8*)&br[64];
        short8 b3 = *(const short8*)&br[96];
        floatx4 acc = {0.f, 0.f, 0.f, 0.f};
        acc = __builtin_amdgcn_mfma_f32_16x16x32_bf16(a0, b0, acc, 0, 0, 0);
        acc = __builtin_amdgcn_mfma_f32_16x16x32_bf16(a1, b1, acc, 0, 0, 0);
        acc = __builtin_amdgcn_mfma_f32_16x16x32_bf16(a2, b2, acc, 0, 0, 0);
        acc = __builtin_amdgcn_mfma_f32_16x16x32_bf16(a3, b3, acc, 0, 0, 0);
        #pragma unroll
        for (int rg = 0; rg < 4; ++rg)
            As[(wid * 16 + q * 4 + rg) * 136 + ct * 16 + m] = bf16bits(acc[rg]);
    }
    __syncthreads();

    for (int i = threadIdx.x; i < 1024; i += 256) {  // 64 rows x 16 chunks(8 u16)
        int r = i >> 4, ch = i & 15;
        *(uint4*)(x1u + (size_t)(r0 + r) * 64 + ch * 4) = *(const uint4*)&As[r * 136 + ch * 8];
    }
}

// ---------------- final gather-max -> dense fp32 output, BN1+ReLU on the fly ----
__global__ void k_vmax1(const uint2* __restrict__ x1u, const int* __restrict__ ucnt,
                        const int* __restrict__ slot, const float* __restrict__ ss,
                        float4* __restrict__ out) {
    __shared__ float s[256];
    s[threadIdx.x] = ss[threadIdx.x];
    __syncthreads();
    int t = blockIdx.x * 256 + threadIdx.x;
    int v = t >> 5;
    if (v >= CANVAS) return;
    int c = (t & 31) << 2;
    int n = min(ucnt[v], CAP);
    float4 m = make_float4(0.f, 0.f, 0.f, 0.f);
    for (int j = 0; j < n; ++j) {
        int p = slot[v * CAP + j];
        uint2 u = x1u[(size_t)p * 32 + (c >> 2)];
        m.x = fmaxf(m.x, fmaf(lo16(u.x), s[c + 0], s[128 + c + 0]));
        m.y = fmaxf(m.y, fmaf(hi16(u.x), s[c + 1], s[128 + c + 1]));
        m.z = fmaxf(m.z, fmaf(lo16(u.y), s[c + 2], s[128 + c + 2]));
        m.w = fmaxf(m.w, fmaf(hi16(u.y), s[c + 3], s[128 + c + 3]));
    }
    out[(size_t)v * 32 + (c >> 2)] = m;
}

extern "C" void kernel_launch(void* const* d_in, const int* in_sizes, int n_in,
                              void* d_out, int out_size, void* d_ws, size_t ws_size,
                              hipStream_t stream) {
    const float4* feat  = (const float4*)d_in[0];
    const int4*   coors = (const int4*)d_in[1];
    const float*  W0    = (const float*)d_in[2];
    const float*  g0    = (const float*)d_in[3];
    const float*  b0    = (const float*)d_in[4];
    const float*  W1    = (const float*)d_in[5];
    const float*  g1    = (const float*)d_in[6];
    const float*  b1    = (const float*)d_in[7];

    char* ws = (char*)d_ws;
    // workspace layout (bytes)
    int*    idxbuf = (int*)(ws + 0);               //   1,600,000
    float*  vsum   = (float*)(ws + 1600000);       //   4,505,600
    int*    ucnt   = (int*)(ws + 6105600);         //   1,126,400
    float*  stats  = (float*)(ws + 7232000);       //   768 floats:
    //   [0:128] sum0|sq0, [128:384] sum1|sq1, [384:512] ss0, [512:768] ss1
    int*    slot   = (int*)(ws + 7235072);         //  18,022,400 (CANVAS*CAP*4)
    ushort* w1t    = (ushort*)(ws + 25257472);     //      32,768
    uint*   x0u    = (uint*)(ws + 25290240);       //  51,200,000 (pre-BN bf16)
    uint*   v0u    = (uint*)(ws + 76490240);       //  36,044,800 (post-BN0-ReLU max, bf16)
    uint*   x1u    = (uint*)(ws + 112535040);      // 102,400,000 (pre-BN1, bf16)
    // total: 214,935,040 bytes

    hipMemsetAsync(ws + 1600000, 0, 5632000, stream);          // vsum + ucnt
    hipMemsetAsync(stats, 0, 384 * sizeof(float), stream);     // sums/sumsqs

    const int BLK = 256;
    int gpts = (NPTS + BLK - 1) / BLK;  // 1563

    k_bucket<<<gpts, BLK, 0, stream>>>(feat, coors, idxbuf, vsum, ucnt, slot);
    k_prepw<<<64, BLK, 0, stream>>>(W1, w1t);
    k_gemm1<<<gpts, BLK, 0, stream>>>(feat, coors, idxbuf, (const float4*)vsum, ucnt, W0, x0u);
    k_colstats_bf<32><<<1024, BLK, 0, stream>>>(x0u, stats);
    k_bnfin<<<1, 64, 0, stream>>>(stats, g0, b0, stats + 384, 64, 1.0f / NPTS);
    k_vmax0<<<CANVAS * 16 / BLK, BLK, 0, stream>>>(x0u, ucnt, slot, stats + 384, v0u);
    k_gemm2m<<<NPTS / 64, BLK, 0, stream>>>(x0u, v0u, idxbuf, stats + 384, w1t, x1u);
    k_colstats_bf<64><<<1024, BLK, 0, stream>>>(x1u, stats + 128);
    k_bnfin<<<1, 128, 0, stream>>>(stats + 128, g1, b1, stats + 512, 128, 1.0f / NPTS);
    k_vmax1<<<CANVAS * 32 / BLK, BLK, 0, stream>>>((const uint2*)x1u, ucnt, slot,
                                                   stats + 512, (float4*)d_out);
}

// Round 4
// 507.131 us; speedup vs baseline: 3.4600x; 1.1689x over previous
//
#include <hip/hip_runtime.h>

#define NPTS 400000
#define NXv 352
#define NYv 400
#define CANVAS 281600  // 2 * 1 * 400 * 352
#define CAP 16         // max tracked points per voxel (Poisson lambda=1.42; P(overflow)~1e-6)
#define NBLK2 6250     // NPTS / 64, gemm2m blocks

typedef unsigned int uint;
typedef unsigned short ushort;
typedef __attribute__((ext_vector_type(8))) short short8;   // 8 bf16 (4 VGPRs)
typedef __attribute__((ext_vector_type(4))) float floatx4;  // MFMA acc

// round-to-nearest-even float -> bf16 pack of two values into one uint (a=low, b=high)
__device__ inline uint packbf(float a, float b) {
    uint ua = __float_as_uint(a);
    ua = (ua + 0x7fffu + ((ua >> 16) & 1u)) >> 16;
    uint ub = __float_as_uint(b);
    ub = (ub + 0x7fffu + ((ub >> 16) & 1u)) & 0xffff0000u;
    return ua | ub;
}
__device__ inline ushort bf16bits(float a) {
    uint u = __float_as_uint(a);
    return (ushort)((u + 0x7fffu + ((u >> 16) & 1u)) >> 16);
}
__device__ inline float lo16(uint u) { return __uint_as_float(u << 16); }
__device__ inline float hi16(uint u) { return __uint_as_float(u & 0xffff0000u); }

// ---------------- K1: bucket build (idx, slot lists, counts) --------------------
__global__ void k_bucket(const int4* __restrict__ coors, int* __restrict__ idxbuf,
                         int* __restrict__ ucnt, int* __restrict__ slot) {
    int i = blockIdx.x * 256 + threadIdx.x;
    if (i >= NPTS) return;
    int4 c = coors[i];                       // [b, z, y, x], NZ == 1
    int idx = ((c.x + c.y) * NYv + c.z) * NXv + c.w;
    idxbuf[i] = idx;
    int pos = atomicAdd(&ucnt[idx], 1);
    if (pos < CAP) slot[idx * CAP + pos] = i;
}

// ---------------- per-voxel mean via gather (plain stores) ----------------------
__global__ void k_vmean(const float4* __restrict__ feat, const int* __restrict__ ucnt,
                        const int* __restrict__ slot, float4* __restrict__ vmean) {
    int v = blockIdx.x * 256 + threadIdx.x;
    if (v >= CANVAS) return;
    int n = ucnt[v];
    int ng = min(n, CAP);
    float4 s = make_float4(0.f, 0.f, 0.f, 0.f);
    for (int j = 0; j < ng; ++j) {
        float4 f = feat[slot[v * CAP + j]];
        s.x += f.x; s.y += f.y; s.z += f.z; s.w += f.w;
    }
    float inv = 1.0f / (float)max(n, 1);
    vmean[v] = make_float4(s.x * inv, s.y * inv, s.z * inv, s.w * inv);
}

// ---------------- W1 (128x128 f32, KxN) -> W1T bf16 (NxK) -----------------------
__global__ void k_prepw(const float* __restrict__ W1, ushort* __restrict__ w1t) {
    int i = blockIdx.x * 256 + threadIdx.x;
    if (i >= 16384) return;
    int n = i & 127, k = i >> 7;
    w1t[n * 128 + k] = bf16bits(W1[k * 128 + n]);
}

// ---------------- K2: build feat(10), GEMM1 (10->64), store pre-BN x0 bf16 ------
__global__ void k_gemm1(const float4* __restrict__ feat, const int4* __restrict__ coors,
                        const int* __restrict__ idxbuf, const float4* __restrict__ vmean,
                        const float* __restrict__ W0, uint* __restrict__ x0u) {
    __shared__ float w0s[640];
    for (int t = threadIdx.x; t < 640; t += 256) w0s[t] = W0[t];
    __syncthreads();
    int i = blockIdx.x * 256 + threadIdx.x;
    if (i >= NPTS) return;
    float4 f = feat[i];
    float4 vm = vmean[idxbuf[i]];
    int4 c = coors[i];
    float ft[10];
    ft[0] = f.x; ft[1] = f.y; ft[2] = f.z; ft[3] = f.w;
    ft[4] = f.x - vm.x;
    ft[5] = f.y - vm.y;
    ft[6] = f.z - vm.z;
    ft[7] = f.x - ((float)c.w * 0.2f + 0.1f);            // VX/2 + PCR0
    ft[8] = f.y - ((float)c.z * 0.2f + (0.1f - 40.0f));  // VY/2 + PCR1
    ft[9] = f.z - ((float)c.y * 4.0f + (2.0f - 3.0f));   // VZ/2 + PCR2
    uint* o = x0u + (size_t)i * 32;
    #pragma unroll
    for (int g = 0; g < 8; ++g) {
        float a[8];
        #pragma unroll
        for (int j = 0; j < 8; ++j) a[j] = 0.f;
        #pragma unroll
        for (int k = 0; k < 10; ++k) {
            float fk = ft[k];
            #pragma unroll
            for (int j = 0; j < 8; ++j) a[j] = fmaf(fk, w0s[k * 64 + g * 8 + j], a[j]);
        }
        uint4 w;
        w.x = packbf(a[0], a[1]); w.y = packbf(a[2], a[3]);
        w.z = packbf(a[4], a[5]); w.w = packbf(a[6], a[7]);
        *(uint4*)(o + g * 4) = w;
    }
}

// ---------------- column stats over bf16-packed matrix (x0: 64 cols) ------------
__global__ void k_colstats0(const uint* __restrict__ x, float* __restrict__ sums) {
    int cp = threadIdx.x & 31;   // column pair
    int sub = threadIdx.x >> 5;  // 0..7
    float s0 = 0.f, s1 = 0.f, q0 = 0.f, q1 = 0.f;
    for (int r = blockIdx.x * 8 + sub; r < NPTS; r += gridDim.x * 8) {
        uint u = x[(size_t)r * 32 + cp];
        float a = lo16(u), b = hi16(u);
        s0 += a; q0 = fmaf(a, a, q0);
        s1 += b; q1 = fmaf(b, b, q1);
    }
    __shared__ float sh[1024];
    sh[threadIdx.x] = s0; sh[256 + threadIdx.x] = q0;
    sh[512 + threadIdx.x] = s1; sh[768 + threadIdx.x] = q1;
    __syncthreads();
    if (sub == 0) {
        #pragma unroll
        for (int k = 1; k < 8; ++k) {
            s0 += sh[cp + k * 32];       q0 += sh[256 + cp + k * 32];
            s1 += sh[512 + cp + k * 32]; q1 += sh[768 + cp + k * 32];
        }
        atomicAdd(&sums[2 * cp + 0], s0);
        atomicAdd(&sums[2 * cp + 1], s1);
        atomicAdd(&sums[64 + 2 * cp + 0], q0);
        atomicAdd(&sums[64 + 2 * cp + 1], q1);
    }
}

// ---------------- BN finalize: scale = g/sqrt(var+eps), shift = b - mu*scale ----
__global__ void k_bnfin(const float* __restrict__ sums, const float* __restrict__ g,
                        const float* __restrict__ b, float* __restrict__ ss, int C,
                        float invN) {
    int j = threadIdx.x;
    if (j >= C) return;
    float mu = sums[j] * invN;
    float var = sums[C + j] * invN - mu * mu;
    float istd = 1.0f / sqrtf(var + 1e-3f);
    float scale = istd * g[j];
    ss[j] = scale;
    ss[C + j] = b[j] - mu * scale;
}

// ---------------- gather-max over voxel lists, BN0+ReLU on the fly, bf16 out ----
__global__ void k_vmax0(const uint* __restrict__ x0u, const int* __restrict__ ucnt,
                        const int* __restrict__ slot, const float* __restrict__ ss,
                        uint* __restrict__ v0u) {
    __shared__ float s[128];
    if (threadIdx.x < 128) s[threadIdx.x] = ss[threadIdx.x];
    __syncthreads();
    int t = blockIdx.x * 256 + threadIdx.x;
    int v = t >> 4;
    if (v >= CANVAS) return;
    int c = (t & 15) << 2;
    int n = min(ucnt[v], CAP);
    float4 m = make_float4(0.f, 0.f, 0.f, 0.f);
    for (int j = 0; j < n; ++j) {
        int p = slot[v * CAP + j];
        uint2 u = *(const uint2*)(x0u + (size_t)p * 32 + (c >> 1));
        m.x = fmaxf(m.x, fmaf(lo16(u.x), s[c + 0], s[64 + c + 0]));
        m.y = fmaxf(m.y, fmaf(hi16(u.x), s[c + 1], s[64 + c + 1]));
        m.z = fmaxf(m.z, fmaf(lo16(u.y), s[c + 2], s[64 + c + 2]));
        m.w = fmaxf(m.w, fmaf(hi16(u.y), s[c + 3], s[64 + c + 3]));
    }
    uint2 o; o.x = packbf(m.x, m.y); o.y = packbf(m.z, m.w);
    *(uint2*)(v0u + (size_t)v * 32 + (c >> 1)) = o;
}

// ---------------- GEMM2 via MFMA + fused column stats ---------------------------
// block = 256 thr (4 waves), strip = 64 points; wave w -> rows [16w,16w+16) x 128 cols
__global__ __launch_bounds__(256) void k_gemm2m(
        const uint* __restrict__ x0u, const uint* __restrict__ v0u,
        const int* __restrict__ idxbuf, const float* __restrict__ ss,
        const ushort* __restrict__ w1t, uint* __restrict__ x1u,
        float* __restrict__ partial) {
    __shared__ __align__(16) ushort Bs[128 * 136];  // W1T, row pad +8
    __shared__ __align__(16) ushort As[64 * 136];   // A tile, reused as C tile
    __shared__ float pst[4096];                     // [wid*4+q][col] sums | +2048 sq
    __shared__ float s[128];
    __shared__ int idxs[64];

    int r0 = blockIdx.x * 64;
    for (int i = threadIdx.x; i < 2048; i += 256) {  // 128 rows x 16 chunks(8 u16)
        int r = i >> 4, ch = i & 15;
        *(uint4*)&Bs[r * 136 + ch * 8] = *(const uint4*)&w1t[r * 128 + ch * 8];
    }
    if (threadIdx.x < 128) s[threadIdx.x] = ss[threadIdx.x];
    if (threadIdx.x < 64) idxs[threadIdx.x] = idxbuf[r0 + threadIdx.x];
    __syncthreads();

    // A cols [0:64) = bnrelu0(x0) ; cols [64:128) = v0[idx] (already post-BN0)
    for (int i = threadIdx.x; i < 512; i += 256) {   // 64 rows x 8 chunks
        int r = i >> 3, ch = i & 7, cb = ch * 8;
        uint4 u = *(const uint4*)(x0u + (size_t)(r0 + r) * 32 + ch * 4);
        uint w[4] = {u.x, u.y, u.z, u.w}, o[4];
        #pragma unroll
        for (int q2 = 0; q2 < 4; ++q2) {
            float a = fmaxf(fmaf(lo16(w[q2]), s[cb + 2 * q2], s[64 + cb + 2 * q2]), 0.f);
            float b = fmaxf(fmaf(hi16(w[q2]), s[cb + 2 * q2 + 1], s[64 + cb + 2 * q2 + 1]), 0.f);
            o[q2] = packbf(a, b);
        }
        *(uint4*)&As[r * 136 + ch * 8] = make_uint4(o[0], o[1], o[2], o[3]);
    }
    for (int i = threadIdx.x; i < 512; i += 256) {
        int r = i >> 3, ch = i & 7;
        *(uint4*)&As[r * 136 + 64 + ch * 8] =
            *(const uint4*)(v0u + (size_t)idxs[r] * 32 + ch * 4);
    }
    __syncthreads();

    int lane = threadIdx.x & 63, wid = threadIdx.x >> 6;
    int m = lane & 15, q = lane >> 4;  // C: col=m', row=q*4+reg
    const ushort* ar = &As[(wid * 16 + m) * 136 + q * 8];
    short8 a0 = *(const short8*)&ar[0];
    short8 a1 = *(const short8*)&ar[32];
    short8 a2 = *(const short8*)&ar[64];
    short8 a3 = *(const short8*)&ar[96];
    __syncthreads();  // all waves done reading As; reuse it for C

    #pragma unroll
    for (int ct = 0; ct < 8; ++ct) {
        const ushort* br = &Bs[(ct * 16 + m) * 136 + q * 8];
        short8 b0 = *(const short8*)&br[0];
        short8 b1 = *(const short8*)&br[32];
        short8 b2 = *(const short8*)&br[64];
        short8 b3 = *(const short8*)&br[96];
        floatx4 acc = {0.f, 0.f, 0.f, 0.f};
        acc = __builtin_amdgcn_mfma_f32_16x16x32_bf16(a0, b0, acc, 0, 0, 0);
        acc = __builtin_amdgcn_mfma_f32_16x16x32_bf16(a1, b1, acc, 0, 0, 0);
        acc = __builtin_amdgcn_mfma_f32_16x16x32_bf16(a2, b2, acc, 0, 0, 0);
        acc = __builtin_amdgcn_mfma_f32_16x16x32_bf16(a3, b3, acc, 0, 0, 0);
        float ps = acc[0] + acc[1] + acc[2] + acc[3];
        float pq = acc[0] * acc[0];
        pq = fmaf(acc[1], acc[1], pq);
        pq = fmaf(acc[2], acc[2], pq);
        pq = fmaf(acc[3], acc[3], pq);
        int col = ct * 16 + m;
        pst[(wid * 4 + q) * 128 + col] = ps;
        pst[2048 + (wid * 4 + q) * 128 + col] = pq;
        #pragma unroll
        for (int rg = 0; rg < 4; ++rg)
            As[(wid * 16 + q * 4 + rg) * 136 + ct * 16 + m] = bf16bits(acc[rg]);
    }
    __syncthreads();

    // C write-out (bf16) + per-block stats partial (256 floats: [0:128] sum, [128:256] sq)
    for (int i = threadIdx.x; i < 1024; i += 256) {  // 64 rows x 16 chunks(8 u16)
        int r = i >> 4, ch = i & 15;
        *(uint4*)(x1u + (size_t)(r0 + r) * 64 + ch * 4) = *(const uint4*)&As[r * 136 + ch * 8];
    }
    {
        int t = threadIdx.x;
        int base = (t < 128) ? 0 : 2048;
        int c = t & 127;
        float acc = 0.f;
        #pragma unroll
        for (int k = 0; k < 16; ++k) acc += pst[base + k * 128 + c];
        partial[(size_t)blockIdx.x * 256 + t] = acc;
    }
}

// ---------------- reduce gemm2m partials -> sums[0:128]=sum, [128:256]=sq -------
__global__ void k_red(const float* __restrict__ partial, float* __restrict__ sums) {
    int c = threadIdx.x;
    float s = 0.f;
    for (int r = blockIdx.x; r < NBLK2; r += gridDim.x) s += partial[(size_t)r * 256 + c];
    atomicAdd(&sums[c], s);
}

// ---------------- final gather-max -> dense fp32 output, BN1+ReLU on the fly ----
__global__ void k_vmax1(const uint2* __restrict__ x1u, const int* __restrict__ ucnt,
                        const int* __restrict__ slot, const float* __restrict__ ss,
                        float4* __restrict__ out) {
    __shared__ float s[256];
    s[threadIdx.x] = ss[threadIdx.x];
    __syncthreads();
    int t = blockIdx.x * 256 + threadIdx.x;
    int v = t >> 5;
    if (v >= CANVAS) return;
    int c = (t & 31) << 2;
    int n = min(ucnt[v], CAP);
    float4 m = make_float4(0.f, 0.f, 0.f, 0.f);
    for (int j = 0; j < n; ++j) {
        int p = slot[v * CAP + j];
        uint2 u = x1u[(size_t)p * 32 + (c >> 2)];
        m.x = fmaxf(m.x, fmaf(lo16(u.x), s[c + 0], s[128 + c + 0]));
        m.y = fmaxf(m.y, fmaf(hi16(u.x), s[c + 1], s[128 + c + 1]));
        m.z = fmaxf(m.z, fmaf(lo16(u.y), s[c + 2], s[128 + c + 2]));
        m.w = fmaxf(m.w, fmaf(hi16(u.y), s[c + 3], s[128 + c + 3]));
    }
    out[(size_t)v * 32 + (c >> 2)] = m;
}

extern "C" void kernel_launch(void* const* d_in, const int* in_sizes, int n_in,
                              void* d_out, int out_size, void* d_ws, size_t ws_size,
                              hipStream_t stream) {
    const float4* feat  = (const float4*)d_in[0];
    const int4*   coors = (const int4*)d_in[1];
    const float*  W0    = (const float*)d_in[2];
    const float*  g0    = (const float*)d_in[3];
    const float*  b0    = (const float*)d_in[4];
    const float*  W1    = (const float*)d_in[5];
    const float*  g1    = (const float*)d_in[6];
    const float*  b1    = (const float*)d_in[7];

    char* ws = (char*)d_ws;
    // workspace layout (bytes)
    int*    idxbuf = (int*)(ws + 0);               //   1,600,000
    float*  vmean  = (float*)(ws + 1600000);       //   4,505,600 (float4 per voxel)
    int*    ucnt   = (int*)(ws + 6105600);         //   1,126,400
    float*  stats  = (float*)(ws + 7232000);       //   768 floats:
    //   [0:128] sum0|sq0, [128:384] sum1|sq1, [384:512] ss0, [512:768] ss1
    int*    slot   = (int*)(ws + 7235072);         //  18,022,400 (CANVAS*CAP*4)
    ushort* w1t    = (ushort*)(ws + 25257472);     //      32,768
    uint*   x0u    = (uint*)(ws + 25290240);       //  51,200,000 (pre-BN bf16)
    uint*   v0u    = (uint*)(ws + 76490240);       //  36,044,800 (post-BN0-ReLU max, bf16)
    uint*   x1u    = (uint*)(ws + 112535040);      // 102,400,000 (pre-BN1, bf16)
    float*  part   = (float*)(ws + 214935040);     //   6,400,000 (NBLK2 * 256 f32)
    // total: 221,335,040 bytes

    hipMemsetAsync(ucnt, 0, 1126400, stream);
    hipMemsetAsync(stats, 0, 384 * sizeof(float), stream);

    const int BLK = 256;
    int gpts = (NPTS + BLK - 1) / BLK;    // 1563
    int gvox = (CANVAS + BLK - 1) / BLK;  // 1100

    k_bucket<<<gpts, BLK, 0, stream>>>(coors, idxbuf, ucnt, slot);
    k_prepw<<<64, BLK, 0, stream>>>(W1, w1t);
    k_vmean<<<gvox, BLK, 0, stream>>>(feat, ucnt, slot, (float4*)vmean);
    k_gemm1<<<gpts, BLK, 0, stream>>>(feat, coors, idxbuf, (const float4*)vmean, W0, x0u);
    k_colstats0<<<1024, BLK, 0, stream>>>(x0u, stats);
    k_bnfin<<<1, 64, 0, stream>>>(stats, g0, b0, stats + 384, 64, 1.0f / NPTS);
    k_vmax0<<<CANVAS * 16 / BLK, BLK, 0, stream>>>(x0u, ucnt, slot, stats + 384, v0u);
    k_gemm2m<<<NBLK2, BLK, 0, stream>>>(x0u, v0u, idxbuf, stats + 384, w1t, x1u, part);
    k_red<<<64, BLK, 0, stream>>>(part, stats + 128);
    k_bnfin<<<1, 128, 0, stream>>>(stats + 128, g1, b1, stats + 512, 128, 1.0f / NPTS);
    k_vmax1<<<CANVAS * 32 / BLK, BLK, 0, stream>>>((const uint2*)x1u, ucnt, slot,
                                                   stats + 512, (float4*)d_out);
}

// Round 5
// 453.806 us; speedup vs baseline: 3.8666x; 1.1175x over previous
//
#include <hip/hip_runtime.h>

#define NPTS 400000
#define NXv 352
#define NYv 400
#define CANVAS 281600  // 2 * 1 * 400 * 352
#define NBLK2 6250     // NPTS / 64, gemm2m blocks
#define SCANB 275      // scan blocks: 275 * 1024 == CANVAS

typedef unsigned int uint;
typedef unsigned short ushort;
typedef __attribute__((ext_vector_type(8))) short short8;   // 8 bf16 (4 VGPRs)
typedef __attribute__((ext_vector_type(4))) float floatx4;  // MFMA acc

// round-to-nearest-even float -> bf16 pack of two values into one uint (a=low, b=high)
__device__ inline uint packbf(float a, float b) {
    uint ua = __float_as_uint(a);
    ua = (ua + 0x7fffu + ((ua >> 16) & 1u)) >> 16;
    uint ub = __float_as_uint(b);
    ub = (ub + 0x7fffu + ((ub >> 16) & 1u)) & 0xffff0000u;
    return ua | ub;
}
__device__ inline ushort bf16bits(float a) {
    uint u = __float_as_uint(a);
    return (ushort)((u + 0x7fffu + ((u >> 16) & 1u)) >> 16);
}
__device__ inline float lo16(uint u) { return __uint_as_float(u << 16); }
__device__ inline float hi16(uint u) { return __uint_as_float(u & 0xffff0000u); }
__device__ inline float bfval(ushort u) { return __uint_as_float(((uint)u) << 16); }

// ---------------- K1: voxel id + per-point position + counts --------------------
__global__ void k_bucket(const int4* __restrict__ coors, int* __restrict__ idxbuf,
                         int* __restrict__ pidx, uint* __restrict__ ucnt) {
    int i = blockIdx.x * 256 + threadIdx.x;
    if (i >= NPTS) return;
    int4 c = coors[i];                       // [b, z, y, x], NZ == 1
    int idx = ((c.x + c.y) * NYv + c.z) * NXv + c.w;
    idxbuf[i] = idx;
    pidx[i] = (int)atomicAdd(&ucnt[idx], 1u);
}

// ---------------- exclusive scan of ucnt -> voff (2 kernels) --------------------
__global__ __launch_bounds__(1024) void k_scanA(const uint* __restrict__ ucnt,
                                                uint* __restrict__ voff,
                                                uint* __restrict__ bsum) {
    __shared__ uint sh[1024];
    int t = threadIdx.x;
    int v = blockIdx.x * 1024 + t;
    uint val = ucnt[v];
    sh[t] = val;
    for (int off = 1; off < 1024; off <<= 1) {
        __syncthreads();
        uint x = (t >= off) ? sh[t - off] : 0u;
        __syncthreads();
        sh[t] += x;
    }
    uint incl = sh[t];
    voff[v] = incl - val;           // exclusive within block
    if (t == 1023) bsum[blockIdx.x] = incl;
}

__global__ __launch_bounds__(1024) void k_scanC(const uint* __restrict__ bsum,
                                                uint* __restrict__ voff) {
    __shared__ uint sh[1024];
    __shared__ uint bs[1024];
    int t = threadIdx.x;
    uint val = (t < SCANB) ? bsum[t] : 0u;
    sh[t] = val; bs[t] = val;
    for (int off = 1; off < 1024; off <<= 1) {
        __syncthreads();
        uint x = (t >= off) ? sh[t - off] : 0u;
        __syncthreads();
        sh[t] += x;
    }
    __syncthreads();
    uint off_ = sh[blockIdx.x] - bs[blockIdx.x];  // exclusive block offset
    int v = blockIdx.x * 1024 + t;
    voff[v] += off_;
    if (blockIdx.x == SCANB - 1 && t == 1023) voff[CANVAS] = NPTS;
}

// ---------------- build permutation: sorted position -> original point ----------
__global__ void k_perm(const int* __restrict__ idxbuf, const int* __restrict__ pidx,
                       const uint* __restrict__ voff, int* __restrict__ perm,
                       int* __restrict__ vidx) {
    int i = blockIdx.x * 256 + threadIdx.x;
    if (i >= NPTS) return;
    int idx = idxbuf[i];
    uint j = voff[idx] + (uint)pidx[i];
    perm[j] = i;
    vidx[j] = idx;
}

// ---------------- per-voxel mean via segment gather -----------------------------
__global__ void k_vmean(const float4* __restrict__ feat, const uint* __restrict__ voff,
                        const int* __restrict__ perm, float4* __restrict__ vmean) {
    int v = blockIdx.x * 256 + threadIdx.x;
    if (v >= CANVAS) return;
    uint s_ = voff[v], e_ = voff[v + 1];
    float4 s = make_float4(0.f, 0.f, 0.f, 0.f);
    for (uint j = s_; j < e_; ++j) {
        float4 f = feat[perm[j]];
        s.x += f.x; s.y += f.y; s.z += f.z; s.w += f.w;
    }
    float inv = 1.0f / (float)max((int)(e_ - s_), 1);
    vmean[v] = make_float4(s.x * inv, s.y * inv, s.z * inv, s.w * inv);
}

// ---------------- W1 (128x128 f32, KxN) -> W1T bf16 (NxK) -----------------------
__global__ void k_prepw(const float* __restrict__ W1, ushort* __restrict__ w1t) {
    int i = blockIdx.x * 256 + threadIdx.x;
    if (i >= 16384) return;
    int n = i & 127, k = i >> 7;
    w1t[n * 128 + k] = bf16bits(W1[k * 128 + n]);
}

// ---------------- K2: feat(10) build + GEMM1 + fused column stats ---------------
// sorted-row output; per-block LDS tile -> column sum/sq atomics into stats[0:128]
__global__ __launch_bounds__(256) void k_gemm1(
        const float4* __restrict__ feat, const int4* __restrict__ coors,
        const int* __restrict__ perm, const int* __restrict__ vidx,
        const float4* __restrict__ vmean, const float* __restrict__ W0,
        uint* __restrict__ x0u, float* __restrict__ stats) {
    __shared__ float w0s[640];
    __shared__ __align__(8) ushort tile[256 * 68];  // row pad 68 breaks bank alias
    __shared__ float ps[128], qs[128];
    for (int t = threadIdx.x; t < 640; t += 256) w0s[t] = W0[t];
    __syncthreads();
    int j = blockIdx.x * 256 + threadIdx.x;
    bool valid = j < NPTS;
    ushort* trow = &tile[threadIdx.x * 68];
    if (valid) {
        int i = perm[j];
        float4 f = feat[i];
        int4 c = coors[i];
        float4 vm = vmean[vidx[j]];
        float ft[10];
        ft[0] = f.x; ft[1] = f.y; ft[2] = f.z; ft[3] = f.w;
        ft[4] = f.x - vm.x;
        ft[5] = f.y - vm.y;
        ft[6] = f.z - vm.z;
        ft[7] = f.x - ((float)c.w * 0.2f + 0.1f);            // VX/2 + PCR0
        ft[8] = f.y - ((float)c.z * 0.2f + (0.1f - 40.0f));  // VY/2 + PCR1
        ft[9] = f.z - ((float)c.y * 4.0f + (2.0f - 3.0f));   // VZ/2 + PCR2
        uint* o = x0u + (size_t)j * 32;
        #pragma unroll
        for (int g = 0; g < 8; ++g) {
            float a[8];
            #pragma unroll
            for (int q = 0; q < 8; ++q) a[q] = 0.f;
            #pragma unroll
            for (int k = 0; k < 10; ++k) {
                float fk = ft[k];
                #pragma unroll
                for (int q = 0; q < 8; ++q) a[q] = fmaf(fk, w0s[k * 64 + g * 8 + q], a[q]);
            }
            uint4 w;
            w.x = packbf(a[0], a[1]); w.y = packbf(a[2], a[3]);
            w.z = packbf(a[4], a[5]); w.w = packbf(a[6], a[7]);
            *(uint4*)(o + g * 4) = w;
            ((uint2*)trow)[g * 2 + 0] = make_uint2(w.x, w.y);
            ((uint2*)trow)[g * 2 + 1] = make_uint2(w.z, w.w);
        }
    } else {
        #pragma unroll
        for (int g = 0; g < 16; ++g) ((uint2*)trow)[g] = make_uint2(0u, 0u);
    }
    __syncthreads();
    if (threadIdx.x < 128) {
        int c = threadIdx.x & 63, half = threadIdx.x >> 6;
        float s = 0.f, q = 0.f;
        for (int r = half * 128; r < half * 128 + 128; ++r) {
            float xv = bfval(tile[r * 68 + c]);
            s += xv;
            q = fmaf(xv, xv, q);
        }
        ps[half * 64 + c] = s;
        qs[half * 64 + c] = q;
    }
    __syncthreads();
    if (threadIdx.x < 64) {
        int c = threadIdx.x;
        atomicAdd(&stats[c], ps[c] + ps[64 + c]);
        atomicAdd(&stats[64 + c], qs[c] + qs[64 + c]);
    }
}

// ---------------- BN finalize: scale = g/sqrt(var+eps), shift = b - mu*scale ----
__global__ void k_bnfin(const float* __restrict__ sums, const float* __restrict__ g,
                        const float* __restrict__ b, float* __restrict__ ss, int C,
                        float invN) {
    int j = threadIdx.x;
    if (j >= C) return;
    float mu = sums[j] * invN;
    float var = sums[C + j] * invN - mu * mu;
    float istd = 1.0f / sqrtf(var + 1e-3f);
    float scale = istd * g[j];
    ss[j] = scale;
    ss[C + j] = b[j] - mu * scale;
}

// ---------------- segment-max over sorted x0, BN0+ReLU per point, bf16 out ------
__global__ void k_vmax0(const uint* __restrict__ x0u, const uint* __restrict__ voff,
                        const float* __restrict__ ss, uint* __restrict__ v0u) {
    __shared__ float s[128];
    if (threadIdx.x < 128) s[threadIdx.x] = ss[threadIdx.x];
    __syncthreads();
    int t = blockIdx.x * 256 + threadIdx.x;
    int v = t >> 4;
    if (v >= CANVAS) return;
    int c = (t & 15) << 2;
    uint s_ = voff[v], e_ = voff[v + 1];
    float4 m = make_float4(0.f, 0.f, 0.f, 0.f);
    for (uint j = s_; j < e_; ++j) {
        uint2 u = *(const uint2*)(x0u + (size_t)j * 32 + (c >> 1));
        m.x = fmaxf(m.x, fmaf(lo16(u.x), s[c + 0], s[64 + c + 0]));
        m.y = fmaxf(m.y, fmaf(hi16(u.x), s[c + 1], s[64 + c + 1]));
        m.z = fmaxf(m.z, fmaf(lo16(u.y), s[c + 2], s[64 + c + 2]));
        m.w = fmaxf(m.w, fmaf(hi16(u.y), s[c + 3], s[64 + c + 3]));
    }
    uint2 o; o.x = packbf(m.x, m.y); o.y = packbf(m.z, m.w);
    *(uint2*)(v0u + (size_t)v * 32 + (c >> 1)) = o;
}

// ---------------- GEMM2 via MFMA + fused column stats (sorted rows) -------------
__global__ __launch_bounds__(256) void k_gemm2m(
        const uint* __restrict__ x0u, const uint* __restrict__ v0u,
        const int* __restrict__ vidx, const float* __restrict__ ss,
        const ushort* __restrict__ w1t, uint* __restrict__ x1u,
        float* __restrict__ partial) {
    __shared__ __align__(16) ushort Bs[128 * 136];  // W1T, row pad +8
    __shared__ __align__(16) ushort As[64 * 136];   // A tile, reused as C tile
    __shared__ float pst[4096];                     // [wid*4+q][col] sums | +2048 sq
    __shared__ float s[128];
    __shared__ int idxs[64];

    int r0 = blockIdx.x * 64;
    for (int i = threadIdx.x; i < 2048; i += 256) {  // 128 rows x 16 chunks(8 u16)
        int r = i >> 4, ch = i & 15;
        *(uint4*)&Bs[r * 136 + ch * 8] = *(const uint4*)&w1t[r * 128 + ch * 8];
    }
    if (threadIdx.x < 128) s[threadIdx.x] = ss[threadIdx.x];
    if (threadIdx.x < 64) idxs[threadIdx.x] = vidx[r0 + threadIdx.x];
    __syncthreads();

    // A cols [0:64) = bnrelu0(x0) ; cols [64:128) = v0[vidx] (already post-BN0)
    for (int i = threadIdx.x; i < 512; i += 256) {   // 64 rows x 8 chunks
        int r = i >> 3, ch = i & 7, cb = ch * 8;
        uint4 u = *(const uint4*)(x0u + (size_t)(r0 + r) * 32 + ch * 4);
        uint w[4] = {u.x, u.y, u.z, u.w}, o[4];
        #pragma unroll
        for (int q2 = 0; q2 < 4; ++q2) {
            float a = fmaxf(fmaf(lo16(w[q2]), s[cb + 2 * q2], s[64 + cb + 2 * q2]), 0.f);
            float b = fmaxf(fmaf(hi16(w[q2]), s[cb + 2 * q2 + 1], s[64 + cb + 2 * q2 + 1]), 0.f);
            o[q2] = packbf(a, b);
        }
        *(uint4*)&As[r * 136 + ch * 8] = make_uint4(o[0], o[1], o[2], o[3]);
    }
    for (int i = threadIdx.x; i < 512; i += 256) {
        int r = i >> 3, ch = i & 7;
        *(uint4*)&As[r * 136 + 64 + ch * 8] =
            *(const uint4*)(v0u + (size_t)idxs[r] * 32 + ch * 4);
    }
    __syncthreads();

    int lane = threadIdx.x & 63, wid = threadIdx.x >> 6;
    int m = lane & 15, q = lane >> 4;  // C: col=m', row=q*4+reg
    const ushort* ar = &As[(wid * 16 + m) * 136 + q * 8];
    short8 a0 = *(const short8*)&ar[0];
    short8 a1 = *(const short8*)&ar[32];
    short8 a2 = *(const short8*)&ar[64];
    short8 a3 = *(const short8*)&ar[96];
    __syncthreads();  // all waves done reading As; reuse it for C

    #pragma unroll
    for (int ct = 0; ct < 8; ++ct) {
        const ushort* br = &Bs[(ct * 16 + m) * 136 + q * 8];
        short8 b0 = *(const short8*)&br[0];
        short8 b1 = *(const short8*)&br[32];
        short8 b2 = *(const short8*)&br[64];
        short8 b3 = *(const short8*)&br[96];
        floatx4 acc = {0.f, 0.f, 0.f, 0.f};
        acc = __builtin_amdgcn_mfma_f32_16x16x32_bf16(a0, b0, acc, 0, 0, 0);
        acc = __builtin_amdgcn_mfma_f32_16x16x32_bf16(a1, b1, acc, 0, 0, 0);
        acc = __builtin_amdgcn_mfma_f32_16x16x32_bf16(a2, b2, acc, 0, 0, 0);
        acc = __builtin_amdgcn_mfma_f32_16x16x32_bf16(a3, b3, acc, 0, 0, 0);
        float psv = acc[0] + acc[1] + acc[2] + acc[3];
        float pq = acc[0] * acc[0];
        pq = fmaf(acc[1], acc[1], pq);
        pq = fmaf(acc[2], acc[2], pq);
        pq = fmaf(acc[3], acc[3], pq);
        int col = ct * 16 + m;
        pst[(wid * 4 + q) * 128 + col] = psv;
        pst[2048 + (wid * 4 + q) * 128 + col] = pq;
        #pragma unroll
        for (int rg = 0; rg < 4; ++rg)
            As[(wid * 16 + q * 4 + rg) * 136 + ct * 16 + m] = bf16bits(acc[rg]);
    }
    __syncthreads();

    for (int i = threadIdx.x; i < 1024; i += 256) {  // 64 rows x 16 chunks(8 u16)
        int r = i >> 4, ch = i & 15;
        *(uint4*)(x1u + (size_t)(r0 + r) * 64 + ch * 4) = *(const uint4*)&As[r * 136 + ch * 8];
    }
    {
        int t = threadIdx.x;
        int base = (t < 128) ? 0 : 2048;
        int c = t & 127;
        float acc = 0.f;
        #pragma unroll
        for (int k = 0; k < 16; ++k) acc += pst[base + k * 128 + c];
        partial[(size_t)blockIdx.x * 256 + t] = acc;
    }
}

// ---------------- reduce gemm2m partials -> sums[0:128]=sum, [128:256]=sq -------
__global__ void k_red(const float* __restrict__ partial, float* __restrict__ sums) {
    int c = threadIdx.x;
    float s = 0.f;
    for (int r = blockIdx.x; r < NBLK2; r += gridDim.x) s += partial[(size_t)r * 256 + c];
    atomicAdd(&sums[c], s);
}

// ---------------- segment-max over sorted x1 -> dense fp32 output ---------------
__global__ void k_vmax1(const uint2* __restrict__ x1u, const uint* __restrict__ voff,
                        const float* __restrict__ ss, float4* __restrict__ out) {
    __shared__ float s[256];
    s[threadIdx.x] = ss[threadIdx.x];
    __syncthreads();
    int t = blockIdx.x * 256 + threadIdx.x;
    int v = t >> 5;
    if (v >= CANVAS) return;
    int c = (t & 31) << 2;
    uint s_ = voff[v], e_ = voff[v + 1];
    float4 m = make_float4(0.f, 0.f, 0.f, 0.f);
    for (uint j = s_; j < e_; ++j) {
        uint2 u = x1u[(size_t)j * 32 + (c >> 2)];
        m.x = fmaxf(m.x, fmaf(lo16(u.x), s[c + 0], s[128 + c + 0]));
        m.y = fmaxf(m.y, fmaf(hi16(u.x), s[c + 1], s[128 + c + 1]));
        m.z = fmaxf(m.z, fmaf(lo16(u.y), s[c + 2], s[128 + c + 2]));
        m.w = fmaxf(m.w, fmaf(hi16(u.y), s[c + 3], s[128 + c + 3]));
    }
    out[(size_t)v * 32 + (c >> 2)] = m;
}

extern "C" void kernel_launch(void* const* d_in, const int* in_sizes, int n_in,
                              void* d_out, int out_size, void* d_ws, size_t ws_size,
                              hipStream_t stream) {
    const float4* feat  = (const float4*)d_in[0];
    const int4*   coors = (const int4*)d_in[1];
    const float*  W0    = (const float*)d_in[2];
    const float*  g0    = (const float*)d_in[3];
    const float*  b0    = (const float*)d_in[4];
    const float*  W1    = (const float*)d_in[5];
    const float*  g1    = (const float*)d_in[6];
    const float*  b1    = (const float*)d_in[7];

    char* ws = (char*)d_ws;
    // workspace layout (bytes)
    int*    idxbuf = (int*)(ws + 0);               //   1,600,000
    int*    pidx   = (int*)(ws + 1600000);         //   1,600,000
    uint*   ucnt   = (uint*)(ws + 3200000);        //   1,126,400
    uint*   voff   = (uint*)(ws + 4326400);        //   1,126,416 (CANVAS+1)
    uint*   bsum   = (uint*)(ws + 5452816);        //       1,120
    float*  stats  = (float*)(ws + 5453936);       //       3,072 (768 floats):
    //   [0:128] sum0|sq0, [128:384] sum1|sq1, [384:512] ss0, [512:768] ss1
    int*    perm   = (int*)(ws + 5457008);         //   1,600,000
    int*    vidx   = (int*)(ws + 7057008);         //   1,600,000
    float*  vmean  = (float*)(ws + 8657008);       //   4,505,600
    ushort* w1t    = (ushort*)(ws + 13162608);     //      32,768
    uint*   x0u    = (uint*)(ws + 13195376);       //  51,200,000 (pre-BN bf16, sorted)
    uint*   v0u    = (uint*)(ws + 64395376);       //  36,044,800 (post-BN0-ReLU max, bf16)
    uint*   x1u    = (uint*)(ws + 100440176);      // 102,400,000 (pre-BN1 bf16, sorted)
    float*  part   = (float*)(ws + 202840176);     //   6,400,000 (NBLK2 * 256 f32)
    // total: 209,240,176 bytes

    hipMemsetAsync(ucnt, 0, 1126400, stream);
    hipMemsetAsync(stats, 0, 384 * sizeof(float), stream);

    const int BLK = 256;
    int gpts = (NPTS + BLK - 1) / BLK;    // 1563
    int gvox = (CANVAS + BLK - 1) / BLK;  // 1100

    k_bucket<<<gpts, BLK, 0, stream>>>(coors, idxbuf, pidx, ucnt);
    k_prepw<<<64, BLK, 0, stream>>>(W1, w1t);
    k_scanA<<<SCANB, 1024, 0, stream>>>(ucnt, voff, bsum);
    k_scanC<<<SCANB, 1024, 0, stream>>>(bsum, voff);
    k_perm<<<gpts, BLK, 0, stream>>>(idxbuf, pidx, voff, perm, vidx);
    k_vmean<<<gvox, BLK, 0, stream>>>(feat, voff, perm, (float4*)vmean);
    k_gemm1<<<gpts, BLK, 0, stream>>>(feat, coors, perm, vidx, (const float4*)vmean,
                                      W0, x0u, stats);
    k_bnfin<<<1, 64, 0, stream>>>(stats, g0, b0, stats + 384, 64, 1.0f / NPTS);
    k_vmax0<<<CANVAS * 16 / BLK, BLK, 0, stream>>>(x0u, voff, stats + 384, v0u);
    k_gemm2m<<<NBLK2, BLK, 0, stream>>>(x0u, v0u, vidx, stats + 384, w1t, x1u, part);
    k_red<<<64, BLK, 0, stream>>>(part, stats + 128);
    k_bnfin<<<1, 128, 0, stream>>>(stats + 128, g1, b1, stats + 512, 128, 1.0f / NPTS);
    k_vmax1<<<CANVAS * 32 / BLK, BLK, 0, stream>>>((const uint2*)x1u, voff,
                                                   stats + 512, (float4*)d_out);
}

// Round 6
// 397.176 us; speedup vs baseline: 4.4179x; 1.1426x over previous
//
#include <hip/hip_runtime.h>

#define NPTS 400000
#define NXv 352
#define NYv 400
#define CANVAS 281600  // 2 * 1 * 400 * 352
#define NBLK2 6250     // NPTS / 64 strips for gemm2
#define G2B 512        // persistent gemm2 blocks (2 per CU resident)
#define SCANB 275      // scan blocks: 275 * 1024 == CANVAS

typedef unsigned int uint;
typedef unsigned short ushort;
typedef __attribute__((ext_vector_type(8))) short short8;   // 8 bf16 (4 VGPRs)
typedef __attribute__((ext_vector_type(4))) float floatx4;  // MFMA acc

// round-to-nearest-even float -> bf16 pack of two values into one uint (a=low, b=high)
__device__ inline uint packbf(float a, float b) {
    uint ua = __float_as_uint(a);
    ua = (ua + 0x7fffu + ((ua >> 16) & 1u)) >> 16;
    uint ub = __float_as_uint(b);
    ub = (ub + 0x7fffu + ((ub >> 16) & 1u)) & 0xffff0000u;
    return ua | ub;
}
__device__ inline ushort bf16bits(float a) {
    uint u = __float_as_uint(a);
    return (ushort)((u + 0x7fffu + ((u >> 16) & 1u)) >> 16);
}
__device__ inline float lo16(uint u) { return __uint_as_float(u << 16); }
__device__ inline float hi16(uint u) { return __uint_as_float(u & 0xffff0000u); }
__device__ inline float bfval(ushort u) { return __uint_as_float(((uint)u) << 16); }

// ---------------- K1: voxel id + per-point position + counts  (+ fused W1 prep) -
__global__ void k_bucket(const int4* __restrict__ coors, const float* __restrict__ W1,
                         int* __restrict__ idxbuf, int* __restrict__ pidx,
                         uint* __restrict__ ucnt, ushort* __restrict__ w1t) {
    int b = blockIdx.x;
    if (b < 1563) {
        int i = b * 256 + threadIdx.x;
        if (i >= NPTS) return;
        int4 c = coors[i];                       // [b, z, y, x], NZ == 1
        int idx = ((c.x + c.y) * NYv + c.z) * NXv + c.w;
        idxbuf[i] = idx;
        pidx[i] = (int)atomicAdd(&ucnt[idx], 1u);
    } else {
        int i = (b - 1563) * 256 + threadIdx.x;  // 0..16383: W1 (KxN) -> W1T bf16 (NxK)
        int n = i & 127, k = i >> 7;
        w1t[n * 128 + k] = bf16bits(W1[k * 128 + n]);
    }
}

// ---------------- exclusive scan of ucnt -> voff (2 kernels) --------------------
__global__ __launch_bounds__(1024) void k_scanA(const uint* __restrict__ ucnt,
                                                uint* __restrict__ voff,
                                                uint* __restrict__ bsum) {
    __shared__ uint sh[1024];
    int t = threadIdx.x;
    int v = blockIdx.x * 1024 + t;
    uint val = ucnt[v];
    sh[t] = val;
    for (int off = 1; off < 1024; off <<= 1) {
        __syncthreads();
        uint x = (t >= off) ? sh[t - off] : 0u;
        __syncthreads();
        sh[t] += x;
    }
    uint incl = sh[t];
    voff[v] = incl - val;           // exclusive within block
    if (t == 1023) bsum[blockIdx.x] = incl;
}

__global__ __launch_bounds__(1024) void k_scanC(const uint* __restrict__ bsum,
                                                uint* __restrict__ voff) {
    __shared__ uint sh[1024];
    __shared__ uint bs[1024];
    int t = threadIdx.x;
    uint val = (t < SCANB) ? bsum[t] : 0u;
    sh[t] = val; bs[t] = val;
    for (int off = 1; off < 1024; off <<= 1) {
        __syncthreads();
        uint x = (t >= off) ? sh[t - off] : 0u;
        __syncthreads();
        sh[t] += x;
    }
    __syncthreads();
    uint off_ = sh[blockIdx.x] - bs[blockIdx.x];  // exclusive block offset
    int v = blockIdx.x * 1024 + t;
    voff[v] += off_;
    if (blockIdx.x == SCANB - 1 && t == 1023) voff[CANVAS] = NPTS;
}

// ---------------- permutation + feature sort: featS[j] = feat[i] ----------------
// sequential feat read; scattered 16B write lands in L2 (featS is 6.4 MB)
__global__ void k_perm(const int* __restrict__ idxbuf, const int* __restrict__ pidx,
                       const uint* __restrict__ voff, const float4* __restrict__ feat,
                       int* __restrict__ vidx, float4* __restrict__ featS) {
    int i = blockIdx.x * 256 + threadIdx.x;
    if (i >= NPTS) return;
    int idx = idxbuf[i];
    uint j = voff[idx] + (uint)pidx[i];
    vidx[j] = idx;
    featS[j] = feat[i];
}

// ---------------- per-voxel mean via sequential segment scan --------------------
__global__ void k_vmean(const float4* __restrict__ featS, const uint* __restrict__ voff,
                        float4* __restrict__ vmean) {
    int v = blockIdx.x * 256 + threadIdx.x;
    if (v >= CANVAS) return;
    uint s_ = voff[v], e_ = voff[v + 1];
    float4 s = make_float4(0.f, 0.f, 0.f, 0.f);
    for (uint j = s_; j < e_; ++j) {
        float4 f = featS[j];
        s.x += f.x; s.y += f.y; s.z += f.z; s.w += f.w;
    }
    float inv = 1.0f / (float)max((int)(e_ - s_), 1);
    vmean[v] = make_float4(s.x * inv, s.y * inv, s.z * inv, s.w * inv);
}

// ---------------- K2: feat(10) build + GEMM1 + fused column stats ---------------
// fully sequential reads (featS sorted); voxel coords decoded from vidx
__global__ __launch_bounds__(256) void k_gemm1(
        const float4* __restrict__ featS, const int* __restrict__ vidx,
        const float4* __restrict__ vmean, const float* __restrict__ W0,
        uint* __restrict__ x0u, float* __restrict__ stats) {
    __shared__ float w0s[640];
    __shared__ __align__(8) ushort tile[256 * 68];  // row pad 68 breaks bank alias
    __shared__ float ps[128], qs[128];
    for (int t = threadIdx.x; t < 640; t += 256) w0s[t] = W0[t];
    __syncthreads();
    int j = blockIdx.x * 256 + threadIdx.x;
    bool valid = j < NPTS;
    ushort* trow = &tile[threadIdx.x * 68];
    if (valid) {
        float4 f = featS[j];
        int idx = vidx[j];
        float4 vm = vmean[idx];
        int xq = idx % NXv;            // voxel x
        int yq = (idx / NXv) % NYv;    // voxel y  (z == 0 always)
        float ft[10];
        ft[0] = f.x; ft[1] = f.y; ft[2] = f.z; ft[3] = f.w;
        ft[4] = f.x - vm.x;
        ft[5] = f.y - vm.y;
        ft[6] = f.z - vm.z;
        ft[7] = f.x - ((float)xq * 0.2f + 0.1f);    // VX/2 + PCR0
        ft[8] = f.y - ((float)yq * 0.2f - 39.9f);   // VY/2 + PCR1
        ft[9] = f.z + 1.0f;                         // z=0 -> -(VZ/2 + PCR2) = +1
        uint* o = x0u + (size_t)j * 32;
        #pragma unroll
        for (int g = 0; g < 8; ++g) {
            float a[8];
            #pragma unroll
            for (int q = 0; q < 8; ++q) a[q] = 0.f;
            #pragma unroll
            for (int k = 0; k < 10; ++k) {
                float fk = ft[k];
                #pragma unroll
                for (int q = 0; q < 8; ++q) a[q] = fmaf(fk, w0s[k * 64 + g * 8 + q], a[q]);
            }
            uint4 w;
            w.x = packbf(a[0], a[1]); w.y = packbf(a[2], a[3]);
            w.z = packbf(a[4], a[5]); w.w = packbf(a[6], a[7]);
            *(uint4*)(o + g * 4) = w;
            ((uint2*)trow)[g * 2 + 0] = make_uint2(w.x, w.y);
            ((uint2*)trow)[g * 2 + 1] = make_uint2(w.z, w.w);
        }
    } else {
        #pragma unroll
        for (int g = 0; g < 16; ++g) ((uint2*)trow)[g] = make_uint2(0u, 0u);
    }
    __syncthreads();
    if (threadIdx.x < 128) {
        int c = threadIdx.x & 63, half = threadIdx.x >> 6;
        float s = 0.f, q = 0.f;
        for (int r = half * 128; r < half * 128 + 128; ++r) {
            float xv = bfval(tile[r * 68 + c]);
            s += xv;
            q = fmaf(xv, xv, q);
        }
        ps[half * 64 + c] = s;
        qs[half * 64 + c] = q;
    }
    __syncthreads();
    if (threadIdx.x < 64) {
        int c = threadIdx.x;
        atomicAdd(&stats[c], ps[c] + ps[64 + c]);
        atomicAdd(&stats[64 + c], qs[c] + qs[64 + c]);
    }
}

// ---------------- BN finalize: scale = g/sqrt(var+eps), shift = b - mu*scale ----
__global__ void k_bnfin(const float* __restrict__ sums, const float* __restrict__ g,
                        const float* __restrict__ b, float* __restrict__ ss, int C,
                        float invN) {
    int j = threadIdx.x;
    if (j >= C) return;
    float mu = sums[j] * invN;
    float var = sums[C + j] * invN - mu * mu;
    float istd = 1.0f / sqrtf(var + 1e-3f);
    float scale = istd * g[j];
    ss[j] = scale;
    ss[C + j] = b[j] - mu * scale;
}

// ---------------- segment-max over sorted x0, BN0+ReLU per point, bf16 out ------
__global__ void k_vmax0(const uint* __restrict__ x0u, const uint* __restrict__ voff,
                        const float* __restrict__ ss, uint* __restrict__ v0u) {
    __shared__ float s[128];
    if (threadIdx.x < 128) s[threadIdx.x] = ss[threadIdx.x];
    __syncthreads();
    int t = blockIdx.x * 256 + threadIdx.x;
    int v = t >> 4;
    if (v >= CANVAS) return;
    int c = (t & 15) << 2;
    uint s_ = voff[v], e_ = voff[v + 1];
    float4 m = make_float4(0.f, 0.f, 0.f, 0.f);
    for (uint j = s_; j < e_; ++j) {
        uint2 u = *(const uint2*)(x0u + (size_t)j * 32 + (c >> 1));
        m.x = fmaxf(m.x, fmaf(lo16(u.x), s[c + 0], s[64 + c + 0]));
        m.y = fmaxf(m.y, fmaf(hi16(u.x), s[c + 1], s[64 + c + 1]));
        m.z = fmaxf(m.z, fmaf(lo16(u.y), s[c + 2], s[64 + c + 2]));
        m.w = fmaxf(m.w, fmaf(hi16(u.y), s[c + 3], s[64 + c + 3]));
    }
    uint2 o; o.x = packbf(m.x, m.y); o.y = packbf(m.z, m.w);
    *(uint2*)(v0u + (size_t)v * 32 + (c >> 1)) = o;
}

// ---------------- GEMM2, persistent MFMA + fused column stats -------------------
// G2B blocks, each loops over 64-row strips; W1T staged in LDS once per block;
// 2 barriers per strip; stats accumulated in registers, one atomic pass at end.
__global__ __launch_bounds__(256) void k_gemm2p(
        const uint* __restrict__ x0u, const uint* __restrict__ v0u,
        const int* __restrict__ vidx, const float* __restrict__ ss,
        const ushort* __restrict__ w1t, uint* __restrict__ x1u,
        float* __restrict__ sums) {
    __shared__ __align__(16) ushort Bs[128 * 136];  // W1T, row pad +8
    __shared__ __align__(16) ushort As[64 * 136];   // A tile (also end-reduce buf)
    __shared__ __align__(16) ushort Cs[64 * 136];   // C tile
    __shared__ float s[128];

    for (int i = threadIdx.x; i < 2048; i += 256) {  // 128 rows x 16 chunks(8 u16)
        int r = i >> 4, ch = i & 15;
        *(uint4*)&Bs[r * 136 + ch * 8] = *(const uint4*)&w1t[r * 128 + ch * 8];
    }
    if (threadIdx.x < 128) s[threadIdx.x] = ss[threadIdx.x];

    int lane = threadIdx.x & 63, wid = threadIdx.x >> 6;
    int m = lane & 15, q = lane >> 4;   // C: col=ct*16+m, row=q*4+reg
    int cch = threadIdx.x & 15;         // fixed col-chunk in store phase
    float csum[8], csq[8];
    #pragma unroll
    for (int k = 0; k < 8; ++k) { csum[k] = 0.f; csq[k] = 0.f; }
    __syncthreads();  // Bs, s ready

    for (int st = blockIdx.x; st < NBLK2; st += G2B) {
        int r0 = st * 64;
        // A cols [0:64) = bnrelu0(x0); cols [64:128) = v0[vidx] (post-BN0 already)
        for (int i = threadIdx.x; i < 512; i += 256) {   // 64 rows x 8 chunks
            int r = i >> 3, ch = i & 7, cb = ch * 8;
            uint4 u = *(const uint4*)(x0u + (size_t)(r0 + r) * 32 + ch * 4);
            uint w[4] = {u.x, u.y, u.z, u.w}, o[4];
            #pragma unroll
            for (int q2 = 0; q2 < 4; ++q2) {
                float a = fmaxf(fmaf(lo16(w[q2]), s[cb + 2 * q2], s[64 + cb + 2 * q2]), 0.f);
                float b = fmaxf(fmaf(hi16(w[q2]), s[cb + 2 * q2 + 1], s[64 + cb + 2 * q2 + 1]), 0.f);
                o[q2] = packbf(a, b);
            }
            *(uint4*)&As[r * 136 + ch * 8] = make_uint4(o[0], o[1], o[2], o[3]);
        }
        for (int i = threadIdx.x; i < 512; i += 256) {
            int r = i >> 3, ch = i & 7;
            int vv = vidx[r0 + r];                       // 8 threads share -> broadcast
            *(uint4*)&As[r * 136 + 64 + ch * 8] = *(const uint4*)(v0u + (size_t)vv * 32 + ch * 4);
        }
        __syncthreads();  // As ready; also orders prev Cs-store before new Cs-write

        const ushort* ar = &As[(wid * 16 + m) * 136 + q * 8];
        short8 a0 = *(const short8*)&ar[0];
        short8 a1 = *(const short8*)&ar[32];
        short8 a2 = *(const short8*)&ar[64];
        short8 a3 = *(const short8*)&ar[96];
        #pragma unroll
        for (int ct = 0; ct < 8; ++ct) {
            const ushort* br = &Bs[(ct * 16 + m) * 136 + q * 8];
            short8 b0 = *(const short8*)&br[0];
            short8 b1 = *(const short8*)&br[32];
            short8 b2 = *(const short8*)&br[64];
            short8 b3 = *(const short8*)&br[96];
            floatx4 acc = {0.f, 0.f, 0.f, 0.f};
            acc = __builtin_amdgcn_mfma_f32_16x16x32_bf16(a0, b0, acc, 0, 0, 0);
            acc = __builtin_amdgcn_mfma_f32_16x16x32_bf16(a1, b1, acc, 0, 0, 0);
            acc = __builtin_amdgcn_mfma_f32_16x16x32_bf16(a2, b2, acc, 0, 0, 0);
            acc = __builtin_amdgcn_mfma_f32_16x16x32_bf16(a3, b3, acc, 0, 0, 0);
            #pragma unroll
            for (int rg = 0; rg < 4; ++rg)
                Cs[(wid * 16 + q * 4 + rg) * 136 + ct * 16 + m] = bf16bits(acc[rg]);
        }
        __syncthreads();  // Cs ready; As free (frag reads done)

        for (int i = threadIdx.x; i < 1024; i += 256) {  // 64 rows; cch fixed/thread
            int r = i >> 4;
            uint4 cw = *(const uint4*)&Cs[r * 136 + cch * 8];
            *(uint4*)(x1u + (size_t)(r0 + r) * 64 + cch * 4) = cw;
            uint ww[4] = {cw.x, cw.y, cw.z, cw.w};
            #pragma unroll
            for (int k = 0; k < 4; ++k) {
                float a = lo16(ww[k]), b = hi16(ww[k]);
                csum[2 * k + 0] += a; csq[2 * k + 0] = fmaf(a, a, csq[2 * k + 0]);
                csum[2 * k + 1] += b; csq[2 * k + 1] = fmaf(b, b, csq[2 * k + 1]);
            }
        }
    }

    // end: reduce 16 row-groups x 128 cols (reuse As as float scratch)
    __syncthreads();
    float* red = (float*)As;
    int g = threadIdx.x >> 4;
    #pragma unroll
    for (int k = 0; k < 8; ++k) red[g * 128 + cch * 8 + k] = csum[k];
    __syncthreads();
    if (threadIdx.x < 128) {
        float tt = 0.f;
        #pragma unroll
        for (int k = 0; k < 16; ++k) tt += red[k * 128 + threadIdx.x];
        atomicAdd(&sums[threadIdx.x], tt);
    }
    __syncthreads();
    #pragma unroll
    for (int k = 0; k < 8; ++k) red[g * 128 + cch * 8 + k] = csq[k];
    __syncthreads();
    if (threadIdx.x < 128) {
        float tt = 0.f;
        #pragma unroll
        for (int k = 0; k < 16; ++k) tt += red[k * 128 + threadIdx.x];
        atomicAdd(&sums[128 + threadIdx.x], tt);
    }
}

// ---------------- segment-max over sorted x1 -> dense fp32 output ---------------
__global__ void k_vmax1(const uint2* __restrict__ x1u, const uint* __restrict__ voff,
                        const float* __restrict__ ss, float4* __restrict__ out) {
    __shared__ float s[256];
    s[threadIdx.x] = ss[threadIdx.x];
    __syncthreads();
    int t = blockIdx.x * 256 + threadIdx.x;
    int v = t >> 5;
    if (v >= CANVAS) return;
    int c = (t & 31) << 2;
    uint s_ = voff[v], e_ = voff[v + 1];
    float4 m = make_float4(0.f, 0.f, 0.f, 0.f);
    for (uint j = s_; j < e_; ++j) {
        uint2 u = x1u[(size_t)j * 32 + (c >> 2)];
        m.x = fmaxf(m.x, fmaf(lo16(u.x), s[c + 0], s[128 + c + 0]));
        m.y = fmaxf(m.y, fmaf(hi16(u.x), s[c + 1], s[128 + c + 1]));
        m.z = fmaxf(m.z, fmaf(lo16(u.y), s[c + 2], s[128 + c + 2]));
        m.w = fmaxf(m.w, fmaf(hi16(u.y), s[c + 3], s[128 + c + 3]));
    }
    out[(size_t)v * 32 + (c >> 2)] = m;
}

extern "C" void kernel_launch(void* const* d_in, const int* in_sizes, int n_in,
                              void* d_out, int out_size, void* d_ws, size_t ws_size,
                              hipStream_t stream) {
    const float4* feat  = (const float4*)d_in[0];
    const int4*   coors = (const int4*)d_in[1];
    const float*  W0    = (const float*)d_in[2];
    const float*  g0    = (const float*)d_in[3];
    const float*  b0    = (const float*)d_in[4];
    const float*  W1    = (const float*)d_in[5];
    const float*  g1    = (const float*)d_in[6];
    const float*  b1    = (const float*)d_in[7];

    char* ws = (char*)d_ws;
    // workspace layout (bytes)
    int*    idxbuf = (int*)(ws + 0);               //   1,600,000
    int*    pidx   = (int*)(ws + 1600000);         //   1,600,000
    uint*   ucnt   = (uint*)(ws + 3200000);        //   1,126,400 ┐ one memset
    float*  stats  = (float*)(ws + 4326400);       //       3,072 ┘ (768 floats)
    //   [0:128] sum0|sq0, [128:384] sum1|sq1, [384:512] ss0, [512:768] ss1
    uint*   voff   = (uint*)(ws + 4329472);        //   1,126,416 (CANVAS+1)
    uint*   bsum   = (uint*)(ws + 5455888);        //       4,096
    int*    vidx   = (int*)(ws + 5459984);         //   1,600,000
    float*  featS  = (float*)(ws + 7059984);       //   6,400,000 (sorted float4)
    float*  vmean  = (float*)(ws + 13459984);      //   4,505,600
    ushort* w1t    = (ushort*)(ws + 17965584);     //      32,768
    uint*   x0u    = (uint*)(ws + 17998352);       //  51,200,000 (pre-BN bf16, sorted)
    uint*   v0u    = (uint*)(ws + 69198352);       //  36,044,800 (post-BN0-ReLU max, bf16)
    uint*   x1u    = (uint*)(ws + 105243152);      // 102,400,000 (pre-BN1 bf16, sorted)
    // total: 207,643,152 bytes

    hipMemsetAsync(ws + 3200000, 0, 1129472, stream);  // ucnt + stats in one shot

    const int BLK = 256;
    int gpts = (NPTS + BLK - 1) / BLK;    // 1563
    int gvox = (CANVAS + BLK - 1) / BLK;  // 1100

    k_bucket<<<gpts + 64, BLK, 0, stream>>>(coors, W1, idxbuf, pidx, ucnt, w1t);
    k_scanA<<<SCANB, 1024, 0, stream>>>(ucnt, voff, bsum);
    k_scanC<<<SCANB, 1024, 0, stream>>>(bsum, voff);
    k_perm<<<gpts, BLK, 0, stream>>>(idxbuf, pidx, voff, feat, vidx, (float4*)featS);
    k_vmean<<<gvox, BLK, 0, stream>>>((const float4*)featS, voff, (float4*)vmean);
    k_gemm1<<<gpts, BLK, 0, stream>>>((const float4*)featS, vidx, (const float4*)vmean,
                                      W0, x0u, stats);
    k_bnfin<<<1, 64, 0, stream>>>(stats, g0, b0, stats + 384, 64, 1.0f / NPTS);
    k_vmax0<<<CANVAS * 16 / BLK, BLK, 0, stream>>>(x0u, voff, stats + 384, v0u);
    k_gemm2p<<<G2B, BLK, 0, stream>>>(x0u, v0u, vidx, stats + 384, w1t, x1u, stats + 128);
    k_bnfin<<<1, 128, 0, stream>>>(stats + 128, g1, b1, stats + 512, 128, 1.0f / NPTS);
    k_vmax1<<<CANVAS * 32 / BLK, BLK, 0, stream>>>((const uint2*)x1u, voff,
                                                   stats + 512, (float4*)d_out);
}